// Round 11
// baseline (252.868 us; speedup 1.0000x reference)
//
#include <hip/hip_runtime.h>
#include <hip/hip_bf16.h>

#define NN 100000      // nodes
#define NE 200000      // edges (without self loops)
#define NT (NE + NN)   // total edges incl self loops
#define DIN 165
#define PREPB 128
#define INITB 391
#define PACKB 32       // 8192 threads: wB [128 cols][64 k] bf16 pack
#define W1PB 24        // W1 f16 [c][192] pack: 6144 u32
#define MISCGRID (PREPB + INITB + PACKB + W1PB)
#define L2B 3125       // l2f blocks (32-node tiles, NN = 32*3125 exact)
#define XDW ((size_t)NN * DIN)   // total x dwords (16.5M, divisible by 4)
#define G1ROWS 32      // gemm1 rows/block (NN = 3125*32 exact)
#define G1NDMA 21      // 21 KiB staged per 32-row tile (need 21120B, have 21504B)

typedef __attribute__((ext_vector_type(8))) short bf16x8_t;
typedef __attribute__((ext_vector_type(4))) float f32x4_t;
typedef _Float16 h2_t __attribute__((ext_vector_type(2)));
typedef _Float16 f16x8_t __attribute__((ext_vector_type(8)));

#define AS1 __attribute__((address_space(1)))
#define AS3 __attribute__((address_space(3)))

static __device__ __forceinline__ unsigned short f2bf(float f) {
    __hip_bfloat16 b = __float2bfloat16(f);
    return *(unsigned short*)&b;
}
static __device__ __forceinline__ float bfu(unsigned short u) {
    __hip_bfloat16 b = *(__hip_bfloat16*)&u;
    return __bfloat162float(b);
}
static __device__ __forceinline__ unsigned pkh2(float a, float b) {
    h2_t v; v[0] = (_Float16)a; v[1] = (_Float16)b;
    return *(unsigned*)&v;
}

// ---------------- merged prep: W2pT/wsd | CSR init | mlp wB pack | W1 f16 pack | accum zero ----------------

__global__ __launch_bounds__(256) void k_misc(const float* W2, const float* a2s, const float* a2d,
                                              float* wsd, __hip_bfloat16* W2pT,
                                              int* cnt, int* fill,
                                              const float* tsw1, const float* cw1,
                                              __hip_bfloat16* wB,
                                              const float* W1, unsigned* W1pT, float* zbuf,
                                              float* acc3, int* cnt1) {
    int b = blockIdx.x;
    int tid = threadIdx.x;
    if (b < PREPB) {
        int i = b * 256 + tid;                 // [0, 32768)
        // W2pT[c][j] = bf16(W2[kk*512 + h*64 + c]),  j = h*64 + kk
        int c = i >> 9, j = i & 511;
        int hh = j >> 6, kk = j & 63;
        W2pT[i] = __float2bfloat16(W2[kk * 512 + hh * 64 + c]);
        if (b == 0) zbuf[tid] = 0.f;           // zero source for gemm1 DMA padding
        if (b == 0 && tid == 0) { acc3[0] = 0.f; acc3[1] = 0.f; acc3[2] = 0.f; cnt1[0] = 0; }
        if (i < 512) {
            int h = i >> 6, k = i & 63;
            float s = 0.f, d = 0.f;
            for (int cc = 0; cc < 64; cc++) {
                float w = W2[k * 512 + h * 64 + cc];
                s += w * a2s[h * 64 + cc];
                d += w * a2d[h * 64 + cc];
            }
            wsd[i] = s; wsd[512 + i] = d;
        }
    } else if (b < PREPB + INITB) {
        int i = (b - PREPB) * 256 + tid;
        if (i < NN) { cnt[i] = 0; fill[i] = 0; }
    } else if (b < PREPB + INITB + PACKB) {
        int i = (b - PREPB - INITB) * 256 + tid;  // [0, 8192): c*64 + k
        if (i < 8192) {
            int c = i >> 6, k = i & 63;
            float v = (c < 64) ? tsw1[k * 64 + c] : cw1[k * 64 + (c - 64)];
            wB[i] = __float2bfloat16(v);          // [128 cols][64 k]: ts cols 0-63, cls 64-127
        }
    } else {
        int i = (b - PREPB - INITB - PACKB) * 256 + tid;  // [0, 6144): c*96 + kp
        if (i < 6144) {
            int c = i / 96, kp = i - c * 96;
            int k = 2 * kp;
            float f0 = (k < DIN) ? W1[k * 64 + c] : 0.f;
            float f1 = (k + 1 < DIN) ? W1[(k + 1) * 64 + c] : 0.f;
            W1pT[i] = pkh2(f0, f1);               // [c][96] u32 = [c][192] f16, zero-padded K
        }
    }
}

// ---------------- CSR build ----------------

__global__ __launch_bounds__(256) void k_count(const int* dstE, int* cnt) {
    int e = blockIdx.x * 256 + threadIdx.x;
    if (e < NE) atomicAdd(&cnt[dstE[e]], 1);
}

__global__ __launch_bounds__(256) void k_scanA(const int* cnt, int* rowptr, int* bsum) {
    __shared__ int sm[256];
    int t = threadIdx.x;
    int base = blockIdx.x * 1024;
    int v[4]; int s = 0;
    for (int i = 0; i < 4; i++) {
        int idx = base + t * 4 + i;
        v[i] = (idx < NN) ? (cnt[idx] + 1) : 0;
        s += v[i];
    }
    sm[t] = s; __syncthreads();
    for (int off = 1; off < 256; off <<= 1) {
        int x = (t >= off) ? sm[t - off] : 0;
        __syncthreads();
        sm[t] += x;
        __syncthreads();
    }
    int run = sm[t] - s;
    for (int i = 0; i < 4; i++) {
        run += v[i];
        int idx = base + t * 4 + i;
        if (idx < NN) rowptr[idx + 1] = run;
    }
    if (t == 255) bsum[blockIdx.x] = sm[255];
}

// scanC with folded scanB: each block re-derives the exclusive prefix of bsum (nb<=128) in-wave
__global__ __launch_bounds__(256) void k_scanC(const int* bsum, int* rowptr, int nb) {
    __shared__ int pre[128];
    int tid = threadIdx.x;
    if (tid < 64) {
        int lane = tid;
        int v0 = (lane < nb) ? bsum[lane] : 0;
        int v1 = (64 + lane < nb) ? bsum[64 + lane] : 0;
        int s0 = v0;
        for (int off = 1; off < 64; off <<= 1) { int t = __shfl_up(s0, off); if (lane >= off) s0 += t; }
        int tot0 = __shfl(s0, 63);
        int s1 = v1;
        for (int off = 1; off < 64; off <<= 1) { int t = __shfl_up(s1, off); if (lane >= off) s1 += t; }
        pre[lane] = s0 - v0;
        pre[64 + lane] = tot0 + s1 - v1;
    }
    __syncthreads();
    int i = blockIdx.x * 256 + tid;
    if (i < NN) rowptr[i + 1] += pre[i >> 10];
    if (i == 0) rowptr[0] = 0;
}

__global__ __launch_bounds__(256) void k_fill(const int* srcE, const int* dstE,
                                              const int* rowptr, int* fill, int* col, int* rowv) {
    int i = blockIdx.x * 256 + threadIdx.x;
    if (i >= NT) return;
    int s, d;
    if (i < NE) { s = srcE[i]; d = dstE[i]; }
    else        { s = i - NE; d = s; }        // self loop
    int p = rowptr[d] + atomicAdd(&fill[d], 1);
    col[p] = s;
    rowv[p] = d;
}

// ---------------- Layer 1 GEMM (f16 MFMA): 32-row tiles, 128 thr, burst DMA ----------------

__global__ __launch_bounds__(128) void k_gemm1(const float* x, const unsigned* W1pT,
                                               const float* att_s, const float* att_d,
                                               const float* zsrc,
                                               __hip_bfloat16* h1b, float* aad1) {
    __shared__ float X[G1NDMA * 256];          // 21504 B staged tile; reused as h1 bounce
    int tid = threadIdx.x;
    int l = tid & 63, w = tid >> 6;            // w in {0,1}
    int n0 = blockIdx.x * G1ROWS;
    int frow = l & 15, kg = l >> 4;

    // burst-stage whole 32x165 f32 tile (contiguous, 16B-aligned: n0*660B)
    size_t tb = (size_t)n0 * DIN;
    for (int i = w; i < G1NDMA; i += 2) {
        size_t gd = tb + (size_t)i * 256 + (size_t)l * 4;
        const float* g = (gd + 4 <= XDW) ? (x + gd) : (zsrc + l * 4);
        __builtin_amdgcn_global_load_lds((const AS1 float*)g,
                                         (AS3 float*)(X + i * 256), 16, 0, 0);
    }
    // preload ALL B fragments (24 KB W1pT, L2-resident) while DMA flies
    uint4 B[6][4];
    #pragma unroll
    for (int s = 0; s < 6; s++)
        #pragma unroll
        for (int t = 0; t < 4; t++)
            B[s][t] = *(const uint4*)&W1pT[(t * 16 + frow) * 96 + s * 16 + kg * 4];
    __syncthreads();                           // drains vmcnt: tile + B ready

    // 6 MFMA steps, all operands local (over-read past k=165 annihilated by W1pT zero-pad)
    f32x4_t acc[4] = {};
    int rbase = (w * 16 + frow) * DIN + kg * 8;
    #pragma unroll
    for (int s = 0; s < 6; s++) {
        f16x8_t av;
        #pragma unroll
        for (int j = 0; j < 8; j++) av[j] = (_Float16)X[rbase + s * 32 + j];
        #pragma unroll
        for (int t = 0; t < 4; t++)
            acc[t] = __builtin_amdgcn_mfma_f32_16x16x32_f16(av, *(f16x8_t*)&B[s][t], acc[t], 0, 0, 0);
    }

    // attention partials (C/D: col=l&15 -> c=t*16+frow, row=kg*4+q [m89])
    int nw = n0 + w * 16;
    float asv[4], adv[4];
    #pragma unroll
    for (int t = 0; t < 4; t++) {
        int c = t * 16 + frow;
        asv[t] = att_s[c]; adv[t] = att_d[c];
    }
    int hb = (l >> 3) & 1;
    #pragma unroll
    for (int q = 0; q < 4; q++) {
        int n = nw + kg * 4 + q;
        #pragma unroll
        for (int t = 0; t < 4; t++) {
            float sv = acc[t][q] * asv[t];
            float dv = acc[t][q] * adv[t];
            sv += __shfl_xor(sv, 1); sv += __shfl_xor(sv, 2); sv += __shfl_xor(sv, 4);
            dv += __shfl_xor(dv, 1); dv += __shfl_xor(dv, 2); dv += __shfl_xor(dv, 4);
            if ((l & 7) == 0) {
                int h = t * 2 + hb;
                aad1[(size_t)n * 16 + h]     = sv;
                aad1[(size_t)n * 16 + 8 + h] = dv;
            }
        }
    }

    // h1 via LDS bounce -> coalesced 32B/lane stores
    __syncthreads();
    unsigned short* Hw = (unsigned short*)X + w * 1152;    // per-wave [16][72] bf16
    #pragma unroll
    for (int t = 0; t < 4; t++)
        #pragma unroll
        for (int q = 0; q < 4; q++)
            Hw[(kg * 4 + q) * 72 + t * 16 + frow] = f2bf(acc[t][q]);
    int rr = l >> 2, cc = l & 3;
    int n2 = nw + rr;
    unsigned short* dst = (unsigned short*)h1b + (size_t)n2 * 64 + cc * 16;
    *(uint4*)dst       = *(const uint4*)&Hw[rr * 72 + cc * 16];
    *(uint4*)(dst + 8) = *(const uint4*)&Hw[rr * 72 + cc * 16 + 8];
}

// ---------------- per-edge softmax numerators (bf16) ----------------

__global__ __launch_bounds__(256) void k_edgew(const float* aad, const int* col, const int* rowv,
                                               __hip_bfloat16* web) {
    int e = blockIdx.x * 256 + threadIdx.x;
    if (e >= NT) return;
    int s = col[e], d = rowv[e];
    float4 s0 = *(const float4*)&aad[(size_t)s * 16];
    float4 s1 = *(const float4*)&aad[(size_t)s * 16 + 4];
    float4 dd0 = *(const float4*)&aad[(size_t)d * 16 + 8];
    float4 dd1 = *(const float4*)&aad[(size_t)d * 16 + 12];
    float as[8] = {s0.x, s0.y, s0.z, s0.w, s1.x, s1.y, s1.z, s1.w};
    float ad[8] = {dd0.x, dd0.y, dd0.z, dd0.w, dd1.x, dd1.y, dd1.z, dd1.w};
    unsigned p[4];
    #pragma unroll
    for (int q = 0; q < 4; q++) {
        float a0 = as[2*q]   + ad[2*q];
        float a1 = as[2*q+1] + ad[2*q+1];
        a0 = a0 > 0.f ? a0 : 0.2f * a0;
        a1 = a1 > 0.f ? a1 : 0.2f * a1;
        p[q] = (unsigned)f2bf(__expf(a0)) | ((unsigned)f2bf(__expf(a1)) << 16);
    }
    *(uint4*)&web[(size_t)e * 8] = make_uint4(p[0], p[1], p[2], p[3]);
}

// ---------------- Layer-1 aggregation + att2 fused: 8 lanes/node (uint4 gathers) ----------------
// Lane q8 owns channel octet q8*8..+7 == exactly head q8 -> needs only weight w[q8].

__global__ __launch_bounds__(256) void k_agg1f(const __hip_bfloat16* h1b, const __hip_bfloat16* we1b,
                                               const int* rowptr, const int* col,
                                               const float* b1, const float* wsd,
                                               __hip_bfloat16* out1b, float* aad2) {
    int tid = threadIdx.x;
    int q8 = tid & 7;                          // channel octet == head
    int n = blockIdx.x * 32 + (tid >> 3);      // NN = 32*3125 exact
    const unsigned short* h1u = (const unsigned short*)h1b;
    const unsigned short* weu = (const unsigned short*)we1b;
    int rs = rowptr[n], re = rowptr[n + 1];
    float acc[8] = {};
    float den = 0.f;
    for (int eb = rs; eb < re; eb += 4) {
        int c4[4];
        #pragma unroll
        for (int j = 0; j < 4; j++) c4[j] = col[min(eb + j, re - 1)];   // batched col loads
        #pragma unroll
        for (int j = 0; j < 4; j++) {
            int e = min(eb + j, re - 1);
            float w = bfu(weu[(size_t)e * 8 + q8]);                     // head q8 weight
            w = (eb + j < re) ? w : 0.f;                                // predicate after load
            uint4 hv = *(const uint4*)&h1u[(size_t)c4[j] * 64 + q8 * 8];
            den += w;
            acc[0] += w * bfu((unsigned short)(hv.x & 0xffff));
            acc[1] += w * bfu((unsigned short)(hv.x >> 16));
            acc[2] += w * bfu((unsigned short)(hv.y & 0xffff));
            acc[3] += w * bfu((unsigned short)(hv.y >> 16));
            acc[4] += w * bfu((unsigned short)(hv.z & 0xffff));
            acc[5] += w * bfu((unsigned short)(hv.z >> 16));
            acc[6] += w * bfu((unsigned short)(hv.w & 0xffff));
            acc[7] += w * bfu((unsigned short)(hv.w >> 16));
        }
    }
    float inv = 1.0f / (den + 1e-16f);
    float4 b0 = *(const float4*)&b1[q8 * 8];
    float4 b4 = *(const float4*)&b1[q8 * 8 + 4];
    float bb[8] = {b0.x, b0.y, b0.z, b0.w, b4.x, b4.y, b4.z, b4.w};
    unsigned short u[8];
    float r[8];
    #pragma unroll
    for (int k = 0; k < 8; k++) {
        u[k] = f2bf(acc[k] * inv + bb[k]);
        r[k] = bfu(u[k]);                      // the rounded value att2 consumed before
    }
    unsigned short* ou = (unsigned short*)out1b;
    uint4 pk;
    pk.x = (unsigned)u[0] | ((unsigned)u[1] << 16);
    pk.y = (unsigned)u[2] | ((unsigned)u[3] << 16);
    pk.z = (unsigned)u[4] | ((unsigned)u[5] << 16);
    pk.w = (unsigned)u[6] | ((unsigned)u[7] << 16);
    *(uint4*)&ou[(size_t)n * 64 + q8 * 8] = pk;

    // fused att2: p[j] = <out1[n], wsd[j]>, 8-lane butterfly within the node octet
    float p[16];
    #pragma unroll
    for (int j = 0; j < 16; j++) {
        float4 w0 = *(const float4*)&wsd[j * 64 + q8 * 8];
        float4 w4 = *(const float4*)&wsd[j * 64 + q8 * 8 + 4];
        p[j] = r[0] * w0.x + r[1] * w0.y + r[2] * w0.z + r[3] * w0.w
             + r[4] * w4.x + r[5] * w4.y + r[6] * w4.z + r[7] * w4.w;
    }
    #pragma unroll
    for (int s = 1; s < 8; s <<= 1)
        #pragma unroll
        for (int j = 0; j < 16; j++) p[j] += __shfl_xor(p[j], s);
    float p0 = 0.f, p1 = 0.f;
    #pragma unroll
    for (int j = 0; j < 8; j++) {
        p0 = (q8 == j) ? p[j] : p0;
        p1 = (q8 == j) ? p[8 + j] : p1;
    }
    aad2[(size_t)n * 16 + q8]     = p0;
    aad2[(size_t)n * 16 + 8 + q8] = p1;
}

// ---------------- FUSED layer-2: agg2 + gemm2 + mlp heads + CE + final, 32-node tiles ----------------
// LDS 42 KB -> 3 blocks/CU (12 waves/CU, was 8). Phase A: ONE pass, 8 lanes/node, web weights
// (r9's confirmed gather structure). Phase B: rows (w&1)*16 x cols (w>>1)*32, LDS-staged B.
// Phase C/D: rows (w&1)*16, head (w>>1). Final loss via device atomics (last block writes out).

__global__ __launch_bounds__(256) void k_l2f(const __hip_bfloat16* out1b, const __hip_bfloat16* we2b,
                                             const int* rowptr, const int* col,
                                             const __hip_bfloat16* W2pT, const float* b2,
                                             const __hip_bfloat16* wB,
                                             const float* tsb1, const float* cb1,
                                             const float* tsw2, const float* tsb2,
                                             const float* cw2, const float* cb2,
                                             const int* tst, const int* ctg, const unsigned char* msk,
                                             float* acc3, int* cnt1, float* out) {
    __shared__ unsigned short Ax[32 * 512];    // 32 KB agg tile (swizzled); front reused as o2L
    __shared__ unsigned short Bl[64 * 72];     // 9.2 KB B stage
    __shared__ float red[4][3];
    int tid = threadIdx.x;
    int l = tid & 63, w = tid >> 6;
    int n0 = blockIdx.x * 32;
    int frow = l & 15, kg = l >> 4;

    // ---- phase A: 8 lanes/node, ONE pass of 32 nodes, web-based weights ----
    const unsigned short* o1u = (const unsigned short*)out1b;
    const unsigned short* weu = (const unsigned short*)we2b;
    int q8 = tid & 7;
    {
        int j = tid >> 3;                      // node-local [0,32)
        int n = n0 + j;                        // always < NN (NN = 32*L2B)
        int rs = rowptr[n], re = rowptr[n + 1];
        float acc[8][8];
        float den[8];
        #pragma unroll
        for (int h = 0; h < 8; h++) {
            den[h] = 0.f;
            #pragma unroll
            for (int c = 0; c < 8; c++) acc[h][c] = 0.f;
        }
        for (int eb = rs; eb < re; eb += 4) {
            int c4[4];
            #pragma unroll
            for (int jj = 0; jj < 4; jj++) c4[jj] = col[min(eb + jj, re - 1)];
            #pragma unroll
            for (int jj = 0; jj < 4; jj++) {
                int e = min(eb + jj, re - 1);
                uint4 wv = *(const uint4*)&weu[(size_t)e * 8];           // uniform -> broadcast
                uint4 hv = *(const uint4*)&o1u[(size_t)c4[jj] * 64 + q8 * 8];
                float vm = (eb + jj < re) ? 1.f : 0.f;
                float hc[8] = {bfu((unsigned short)(hv.x & 0xffff)), bfu((unsigned short)(hv.x >> 16)),
                               bfu((unsigned short)(hv.y & 0xffff)), bfu((unsigned short)(hv.y >> 16)),
                               bfu((unsigned short)(hv.z & 0xffff)), bfu((unsigned short)(hv.z >> 16)),
                               bfu((unsigned short)(hv.w & 0xffff)), bfu((unsigned short)(hv.w >> 16))};
                float wt[8] = {bfu((unsigned short)(wv.x & 0xffff)), bfu((unsigned short)(wv.x >> 16)),
                               bfu((unsigned short)(wv.y & 0xffff)), bfu((unsigned short)(wv.y >> 16)),
                               bfu((unsigned short)(wv.z & 0xffff)), bfu((unsigned short)(wv.z >> 16)),
                               bfu((unsigned short)(wv.w & 0xffff)), bfu((unsigned short)(wv.w >> 16))};
                #pragma unroll
                for (int h = 0; h < 8; h++) {
                    float ww = wt[h] * vm;
                    den[h] += ww;
                    #pragma unroll
                    for (int c = 0; c < 8; c++) acc[h][c] += ww * hc[c];
                }
            }
        }
        unsigned short* row = &Ax[j * 512];
        #pragma unroll
        for (int h = 0; h < 8; h++) {
            float inv = 1.0f / (den[h] + 1e-16f);
            uint4 pk;
            pk.x = (unsigned)f2bf(acc[h][0] * inv) | ((unsigned)f2bf(acc[h][1] * inv) << 16);
            pk.y = (unsigned)f2bf(acc[h][2] * inv) | ((unsigned)f2bf(acc[h][3] * inv) << 16);
            pk.z = (unsigned)f2bf(acc[h][4] * inv) | ((unsigned)f2bf(acc[h][5] * inv) << 16);
            pk.w = (unsigned)f2bf(acc[h][6] * inv) | ((unsigned)f2bf(acc[h][7] * inv) << 16);
            int blk = (h * 8 + q8) ^ (j & 7);                           // 16B-block swizzle
            *(uint4*)&row[blk * 8] = pk;
        }
    }
    __syncthreads();

    // ---- phase B: gemm2 MFMA; wave w: rows (w&1)*16, cols (w>>1)*32 ----
    const unsigned short* B_g = (const unsigned short*)W2pT;
    int r0 = (w & 1) * 16;
    int c0 = (w >> 1) * 32;
    f32x4_t gacc[2] = {};
    #pragma unroll 1
    for (int k0 = 0; k0 < 512; k0 += 64) {
        #pragma unroll
        for (int ll = 0; ll < 2; ll++) {
            int u = tid + ll * 256;            // [0,512): r = out col (64), seg = 8x8 bf16
            int r = u >> 3, seg = u & 7;
            *(uint4*)&Bl[r * 72 + seg * 8] = *(const uint4*)&B_g[(size_t)r * 512 + k0 + seg * 8];
        }
        __syncthreads();
        #pragma unroll
        for (int kk = 0; kk < 2; kk++) {
            int blk = ((k0 >> 3) + kk * 4 + kg) ^ (frow & 7);
            bf16x8_t a = *(const bf16x8_t*)&Ax[(r0 + frow) * 512 + blk * 8];
            #pragma unroll
            for (int t = 0; t < 2; t++) {
                bf16x8_t bb = *(const bf16x8_t*)&Bl[(c0 + t * 16 + frow) * 72 + kk * 32 + kg * 8];
                gacc[t] = __builtin_amdgcn_mfma_f32_16x16x32_bf16(a, bb, gacc[t], 0, 0, 0);
            }
        }
        __syncthreads();
    }

    // ---- phase C: o2 bf16 -> LDS (reuse Ax front as [32][72]), then mlp1 MFMA vs wB ----
    unsigned short* o2L = Ax;
    #pragma unroll
    for (int t = 0; t < 2; t++) {
        float bias = b2[c0 + t * 16 + frow];
        f32x4_t g = gacc[t];
        #pragma unroll
        for (int q = 0; q < 4; q++)
            o2L[(r0 + kg * 4 + q) * 72 + c0 + t * 16 + frow] = f2bf(0.125f * g[q] + bias);
    }
    __syncthreads();
    const unsigned short* wBu = (const unsigned short*)wB;
    int m0 = (w & 1) * 16;                     // node row band for mlp
    int h0 = (w >> 1) * 64;                    // wB col base: 0 = ts, 64 = cls
    f32x4_t a2c[4] = {};
    #pragma unroll
    for (int kk = 0; kk < 2; kk++) {
        bf16x8_t a2 = *(const bf16x8_t*)&o2L[(m0 + frow) * 72 + kk * 32 + kg * 8];
        #pragma unroll
        for (int t2 = 0; t2 < 4; t2++) {
            bf16x8_t bf = *(const bf16x8_t*)&wBu[(h0 + t2 * 16 + frow) * 64 + kk * 32 + kg * 8];
            a2c[t2] = __builtin_amdgcn_mfma_f32_16x16x32_bf16(a2, bf, a2c[t2], 0, 0, 0);
        }
    }

    // ---- phase D: per-head second layer + CE ----
    float tsl = 0.f, cll = 0.f, mval = 0.f;
    if ((w >> 1) == 0) {
        float lg[4][5];
        #pragma unroll
        for (int q = 0; q < 4; q++)
            #pragma unroll
            for (int t = 0; t < 5; t++) lg[q][t] = 0.f;
        #pragma unroll
        for (int t2 = 0; t2 < 4; t2++) {
            int c = t2 * 16 + frow;
            float bb = tsb1[c];
            float w0 = tsw2[c * 5 + 0], w1 = tsw2[c * 5 + 1], w2 = tsw2[c * 5 + 2],
                  w3 = tsw2[c * 5 + 3], w4 = tsw2[c * 5 + 4];
            #pragma unroll
            for (int q = 0; q < 4; q++) {
                float v = fmaxf(a2c[t2][q] + bb, 0.f);
                lg[q][0] += v * w0; lg[q][1] += v * w1; lg[q][2] += v * w2;
                lg[q][3] += v * w3; lg[q][4] += v * w4;
            }
        }
        #pragma unroll
        for (int q = 0; q < 4; q++)
            #pragma unroll
            for (int t = 0; t < 5; t++) {
                lg[q][t] += __shfl_xor(lg[q][t], 1);
                lg[q][t] += __shfl_xor(lg[q][t], 2);
                lg[q][t] += __shfl_xor(lg[q][t], 4);
                lg[q][t] += __shfl_xor(lg[q][t], 8);
            }
        if (frow == 0) {
            #pragma unroll
            for (int q = 0; q < 4; q++) {
                int n = n0 + m0 + kg * 4 + q;
                float L[5];
                #pragma unroll
                for (int t = 0; t < 5; t++) L[t] = lg[q][t] + tsb2[t];
                float mx = fmaxf(fmaxf(fmaxf(L[0], L[1]), fmaxf(L[2], L[3])), L[4]);
                float se = 0.f;
                #pragma unroll
                for (int t = 0; t < 5; t++) se += __expf(L[t] - mx);
                int tg = tst[n];
                float pick = 0.f;
                #pragma unroll
                for (int t = 0; t < 5; t++) pick += (t == tg) ? L[t] : 0.f;
                tsl += mx + __logf(se) - pick;
            }
        }
    } else {
        float lc[4][2];
        #pragma unroll
        for (int q = 0; q < 4; q++) { lc[q][0] = 0.f; lc[q][1] = 0.f; }
        #pragma unroll
        for (int t2 = 0; t2 < 4; t2++) {
            int c = t2 * 16 + frow;
            float bb = cb1[c];
            float u0 = cw2[c * 2], u1 = cw2[c * 2 + 1];
            #pragma unroll
            for (int q = 0; q < 4; q++) {
                float v = fmaxf(a2c[t2][q] + bb, 0.f);
                lc[q][0] += v * u0; lc[q][1] += v * u1;
            }
        }
        #pragma unroll
        for (int q = 0; q < 4; q++)
            #pragma unroll
            for (int t = 0; t < 2; t++) {
                lc[q][t] += __shfl_xor(lc[q][t], 1);
                lc[q][t] += __shfl_xor(lc[q][t], 2);
                lc[q][t] += __shfl_xor(lc[q][t], 4);
                lc[q][t] += __shfl_xor(lc[q][t], 8);
            }
        if (frow == 0) {
            #pragma unroll
            for (int q = 0; q < 4; q++) {
                int n = n0 + m0 + kg * 4 + q;
                float C0 = lc[q][0] + cb2[0];
                float C1 = lc[q][1] + cb2[1];
                float mx2 = fmaxf(C0, C1);
                float lse2 = mx2 + __logf(__expf(C0 - mx2) + __expf(C1 - mx2));
                float mv = msk[n] ? 1.f : 0.f;
                float pick2 = ctg[n] ? C1 : C0;
                cll += (lse2 - pick2) * mv;
                mval += mv;
            }
        }
    }
    #pragma unroll
    for (int off = 1; off < 64; off <<= 1) {
        tsl  += __shfl_xor(tsl, off);
        cll  += __shfl_xor(cll, off);
        mval += __shfl_xor(mval, off);
    }
    if (l == 0) { red[w][0] = tsl; red[w][1] = cll; red[w][2] = mval; }
    __syncthreads();
    if (tid == 0) {
        float s0 = red[0][0] + red[1][0] + red[2][0] + red[3][0];
        float s1 = red[0][1] + red[1][1] + red[2][1] + red[3][1];
        float s2 = red[0][2] + red[1][2] + red[2][2] + red[3][2];
        atomicAdd(&acc3[0], s0);
        atomicAdd(&acc3[1], s1);
        atomicAdd(&acc3[2], s2);
        __threadfence();
        int old = atomicAdd(cnt1, 1);
        if (old == L2B - 1) {                  // last block finalizes the loss
            float t0 = atomicAdd(&acc3[0], 0.f);
            float t1 = atomicAdd(&acc3[1], 0.f);
            float t2 = atomicAdd(&acc3[2], 0.f);
            out[0] = t1 / t2 + t0 / (float)NN;
        }
    }
}

// ---------------- host ----------------

extern "C" void kernel_launch(void* const* d_in, const int* in_sizes, int n_in,
                              void* d_out, int out_size, void* d_ws, size_t ws_size,
                              hipStream_t stream) {
    const float* x    = (const float*)d_in[0];
    const int*   ei   = (const int*)d_in[1];
    const int*   tst  = (const int*)d_in[2];
    const int*   ctg  = (const int*)d_in[3];
    const unsigned char* msk = (const unsigned char*)d_in[4];
    const float* W1   = (const float*)d_in[5];
    const float* a1s  = (const float*)d_in[6];
    const float* a1d  = (const float*)d_in[7];
    const float* b1   = (const float*)d_in[8];
    const float* W2   = (const float*)d_in[9];
    const float* a2s  = (const float*)d_in[10];
    const float* a2d  = (const float*)d_in[11];
    const float* b2   = (const float*)d_in[12];
    const float* tsw1 = (const float*)d_in[13];
    const float* tsb1 = (const float*)d_in[14];
    const float* tsw2 = (const float*)d_in[15];
    const float* tsb2 = (const float*)d_in[16];
    const float* cw1  = (const float*)d_in[17];
    const float* cb1  = (const float*)d_in[18];
    const float* cw2  = (const float*)d_in[19];
    const float* cb2  = (const float*)d_in[20];
    const int* srcE = ei;
    const int* dstE = ei + NE;

    char* ws = (char*)d_ws;
    size_t off = 0;
    auto alloc = [&](size_t b) { size_t o = off; off = (off + b + 255) & ~(size_t)255; return o; };
    int*   cnt    = (int*)(ws + alloc((size_t)NN * 4));
    int*   fill   = (int*)(ws + alloc((size_t)NN * 4));
    int*   rowptr = (int*)(ws + alloc((size_t)(NN + 1) * 4));
    int*   bsum   = (int*)(ws + alloc(128 * 4));
    int*   col    = (int*)(ws + alloc((size_t)NT * 4));
    int*   rowv   = (int*)(ws + alloc((size_t)NT * 4));
    float* aad1   = (float*)(ws + alloc((size_t)NN * 16 * 4));
    __hip_bfloat16* out1b = (__hip_bfloat16*)(ws + alloc((size_t)NN * 64 * 2));
    float* aad2   = (float*)(ws + alloc((size_t)NN * 16 * 4));
    float* wsd    = (float*)(ws + alloc(1024 * 4));
    __hip_bfloat16* W2pT  = (__hip_bfloat16*)(ws + alloc(32768 * 2));
    __hip_bfloat16* wB    = (__hip_bfloat16*)(ws + alloc(8192 * 2));
    unsigned* W1pT = (unsigned*)(ws + alloc(6144 * 4));
    float* zbuf   = (float*)(ws + alloc(256 * 4));
    __hip_bfloat16* h1b   = (__hip_bfloat16*)(ws + alloc((size_t)NN * 64 * 2));
    __hip_bfloat16* web   = (__hip_bfloat16*)(ws + alloc((size_t)NT * 8 * 2));
    float* acc3   = (float*)(ws + alloc(4 * 4));
    int*   cnt1   = (int*)(ws + alloc(4 * 4));
    (void)ws_size; (void)in_sizes; (void)n_in; (void)out_size;

    int nb_scan = (NN + 1023) / 1024;  // 98

    k_misc<<<MISCGRID, 256, 0, stream>>>(W2, a2s, a2d, wsd, W2pT, cnt, fill,
                                         tsw1, cw1, wB, W1, W1pT, zbuf, acc3, cnt1);
    k_count<<<(NE + 255) / 256, 256, 0, stream>>>(dstE, cnt);
    k_scanA<<<nb_scan, 256, 0, stream>>>(cnt, rowptr, bsum);
    k_scanC<<<(NN + 255) / 256, 256, 0, stream>>>(bsum, rowptr, nb_scan);
    k_fill<<<(NT + 255) / 256, 256, 0, stream>>>(srcE, dstE, rowptr, fill, col, rowv);

    k_gemm1<<<NN / G1ROWS, 128, 0, stream>>>(x, W1pT, a1s, a1d, zbuf, h1b, aad1);
    k_edgew<<<(NT + 255) / 256, 256, 0, stream>>>(aad1, col, rowv, web);
    k_agg1f<<<NN / 32, 256, 0, stream>>>(h1b, web, rowptr, col, b1, wsd, out1b, aad2);
    k_edgew<<<(NT + 255) / 256, 256, 0, stream>>>(aad2, col, rowv, web);

    k_l2f<<<L2B, 256, 0, stream>>>(out1b, web, rowptr, col, W2pT, b2, wB,
                                   tsb1, cb1, tsw2, tsb2, cw2, cb2, tst, ctg, msk,
                                   acc3, cnt1, (float*)d_out);
}

// Round 12
// 214.254 us; speedup vs baseline: 1.1802x; 1.1802x over previous
//
#include <hip/hip_runtime.h>
#include <hip/hip_bf16.h>

#define NN 100000      // nodes
#define NE 200000      // edges (without self loops)
#define NT (NE + NN)   // total edges incl self loops
#define DIN 165
#define PREPB 128
#define INITB 391
#define PACKB 32       // 8192 threads: wB [128 cols][64 k] bf16 pack
#define W1PB 24        // W1 f16 [c][192] pack: 6144 u32
#define MISCGRID (PREPB + INITB + PACKB + W1PB)
#define NODEB 1563     // ceil(NN/64) blocks (64-node tiles)
#define XDW ((size_t)NN * DIN)   // total x dwords (16.5M, divisible by 4)
#define G1ROWS 32      // gemm1 rows/block (NN = 3125*32 exact)
#define G1NDMA 21      // 21 KiB staged per 32-row tile (need 21120B, have 21504B)

typedef __attribute__((ext_vector_type(8))) short bf16x8_t;
typedef __attribute__((ext_vector_type(4))) float f32x4_t;
typedef _Float16 h2_t __attribute__((ext_vector_type(2)));
typedef _Float16 f16x8_t __attribute__((ext_vector_type(8)));

#define AS1 __attribute__((address_space(1)))
#define AS3 __attribute__((address_space(3)))

static __device__ __forceinline__ unsigned short f2bf(float f) {
    __hip_bfloat16 b = __float2bfloat16(f);
    return *(unsigned short*)&b;
}
static __device__ __forceinline__ float bfu(unsigned short u) {
    __hip_bfloat16 b = *(__hip_bfloat16*)&u;
    return __bfloat162float(b);
}
static __device__ __forceinline__ unsigned pkh2(float a, float b) {
    h2_t v; v[0] = (_Float16)a; v[1] = (_Float16)b;
    return *(unsigned*)&v;
}

// ---------------- merged prep: W2pT/wsd | CSR init | mlp wB pack | W1 f16 pack | accum zero ----------------

__global__ __launch_bounds__(256) void k_misc(const float* W2, const float* a2s, const float* a2d,
                                              float* wsd, __hip_bfloat16* W2pT,
                                              int* cnt, int* fill,
                                              const float* tsw1, const float* cw1,
                                              __hip_bfloat16* wB,
                                              const float* W1, unsigned* W1pT, float* zbuf,
                                              float* acc3, int* cnt1) {
    int b = blockIdx.x;
    int tid = threadIdx.x;
    if (b < PREPB) {
        int i = b * 256 + tid;                 // [0, 32768)
        // W2pT[c][j] = bf16(W2[kk*512 + h*64 + c]),  j = h*64 + kk
        int c = i >> 9, j = i & 511;
        int hh = j >> 6, kk = j & 63;
        W2pT[i] = __float2bfloat16(W2[kk * 512 + hh * 64 + c]);
        if (b == 0) zbuf[tid] = 0.f;           // zero source for gemm1 DMA padding
        if (b == 0 && tid == 0) { acc3[0] = 0.f; acc3[1] = 0.f; acc3[2] = 0.f; cnt1[0] = 0; }
        if (i < 512) {
            int h = i >> 6, k = i & 63;
            float s = 0.f, d = 0.f;
            for (int cc = 0; cc < 64; cc++) {
                float w = W2[k * 512 + h * 64 + cc];
                s += w * a2s[h * 64 + cc];
                d += w * a2d[h * 64 + cc];
            }
            wsd[i] = s; wsd[512 + i] = d;
        }
    } else if (b < PREPB + INITB) {
        int i = (b - PREPB) * 256 + tid;
        if (i < NN) { cnt[i] = 0; fill[i] = 0; }
    } else if (b < PREPB + INITB + PACKB) {
        int i = (b - PREPB - INITB) * 256 + tid;  // [0, 8192): c*64 + k
        if (i < 8192) {
            int c = i >> 6, k = i & 63;
            float v = (c < 64) ? tsw1[k * 64 + c] : cw1[k * 64 + (c - 64)];
            wB[i] = __float2bfloat16(v);          // [128 cols][64 k]: ts cols 0-63, cls 64-127
        }
    } else {
        int i = (b - PREPB - INITB - PACKB) * 256 + tid;  // [0, 6144): c*96 + kp
        if (i < 6144) {
            int c = i / 96, kp = i - c * 96;
            int k = 2 * kp;
            float f0 = (k < DIN) ? W1[k * 64 + c] : 0.f;
            float f1 = (k + 1 < DIN) ? W1[(k + 1) * 64 + c] : 0.f;
            W1pT[i] = pkh2(f0, f1);               // [c][96] u32 = [c][192] f16, zero-padded K
        }
    }
}

// ---------------- CSR build ----------------

__global__ __launch_bounds__(256) void k_count(const int* dstE, int* cnt) {
    int e = blockIdx.x * 256 + threadIdx.x;
    if (e < NE) atomicAdd(&cnt[dstE[e]], 1);
}

__global__ __launch_bounds__(256) void k_scanA(const int* cnt, int* rowptr, int* bsum) {
    __shared__ int sm[256];
    int t = threadIdx.x;
    int base = blockIdx.x * 1024;
    int v[4]; int s = 0;
    for (int i = 0; i < 4; i++) {
        int idx = base + t * 4 + i;
        v[i] = (idx < NN) ? (cnt[idx] + 1) : 0;
        s += v[i];
    }
    sm[t] = s; __syncthreads();
    for (int off = 1; off < 256; off <<= 1) {
        int x = (t >= off) ? sm[t - off] : 0;
        __syncthreads();
        sm[t] += x;
        __syncthreads();
    }
    int run = sm[t] - s;
    for (int i = 0; i < 4; i++) {
        run += v[i];
        int idx = base + t * 4 + i;
        if (idx < NN) rowptr[idx + 1] = run;
    }
    if (t == 255) bsum[blockIdx.x] = sm[255];
}

// scanC with folded scanB: each block re-derives the exclusive prefix of bsum (nb<=128) in-wave
__global__ __launch_bounds__(256) void k_scanC(const int* bsum, int* rowptr, int nb) {
    __shared__ int pre[128];
    int tid = threadIdx.x;
    if (tid < 64) {
        int lane = tid;
        int v0 = (lane < nb) ? bsum[lane] : 0;
        int v1 = (64 + lane < nb) ? bsum[64 + lane] : 0;
        int s0 = v0;
        for (int off = 1; off < 64; off <<= 1) { int t = __shfl_up(s0, off); if (lane >= off) s0 += t; }
        int tot0 = __shfl(s0, 63);
        int s1 = v1;
        for (int off = 1; off < 64; off <<= 1) { int t = __shfl_up(s1, off); if (lane >= off) s1 += t; }
        pre[lane] = s0 - v0;
        pre[64 + lane] = tot0 + s1 - v1;
    }
    __syncthreads();
    int i = blockIdx.x * 256 + tid;
    if (i < NN) rowptr[i + 1] += pre[i >> 10];
    if (i == 0) rowptr[0] = 0;
}

__global__ __launch_bounds__(256) void k_fill(const int* srcE, const int* dstE,
                                              const int* rowptr, int* fill, int* col, int* rowv) {
    int i = blockIdx.x * 256 + threadIdx.x;
    if (i >= NT) return;
    int s, d;
    if (i < NE) { s = srcE[i]; d = dstE[i]; }
    else        { s = i - NE; d = s; }        // self loop
    int p = rowptr[d] + atomicAdd(&fill[d], 1);
    col[p] = s;
    rowv[p] = d;
}

// ---------------- Layer 1 GEMM (f16 MFMA): 32-row tiles, 128 thr, burst DMA ----------------

__global__ __launch_bounds__(128) void k_gemm1(const float* x, const unsigned* W1pT,
                                               const float* att_s, const float* att_d,
                                               const float* zsrc,
                                               __hip_bfloat16* h1b, float* aad1) {
    __shared__ float X[G1NDMA * 256];          // 21504 B staged tile; reused as h1 bounce
    int tid = threadIdx.x;
    int l = tid & 63, w = tid >> 6;            // w in {0,1}
    int n0 = blockIdx.x * G1ROWS;
    int frow = l & 15, kg = l >> 4;

    // burst-stage whole 32x165 f32 tile (contiguous, 16B-aligned: n0*660B)
    size_t tb = (size_t)n0 * DIN;
    for (int i = w; i < G1NDMA; i += 2) {
        size_t gd = tb + (size_t)i * 256 + (size_t)l * 4;
        const float* g = (gd + 4 <= XDW) ? (x + gd) : (zsrc + l * 4);
        __builtin_amdgcn_global_load_lds((const AS1 float*)g,
                                         (AS3 float*)(X + i * 256), 16, 0, 0);
    }
    // preload ALL B fragments (24 KB W1pT, L2-resident) while DMA flies
    uint4 B[6][4];
    #pragma unroll
    for (int s = 0; s < 6; s++)
        #pragma unroll
        for (int t = 0; t < 4; t++)
            B[s][t] = *(const uint4*)&W1pT[(t * 16 + frow) * 96 + s * 16 + kg * 4];
    __syncthreads();                           // drains vmcnt: tile + B ready

    // 6 MFMA steps, all operands local (over-read past k=165 annihilated by W1pT zero-pad)
    f32x4_t acc[4] = {};
    int rbase = (w * 16 + frow) * DIN + kg * 8;
    #pragma unroll
    for (int s = 0; s < 6; s++) {
        f16x8_t av;
        #pragma unroll
        for (int j = 0; j < 8; j++) av[j] = (_Float16)X[rbase + s * 32 + j];
        #pragma unroll
        for (int t = 0; t < 4; t++)
            acc[t] = __builtin_amdgcn_mfma_f32_16x16x32_f16(av, *(f16x8_t*)&B[s][t], acc[t], 0, 0, 0);
    }

    // attention partials (C/D: col=l&15 -> c=t*16+frow, row=kg*4+q [m89])
    int nw = n0 + w * 16;
    float asv[4], adv[4];
    #pragma unroll
    for (int t = 0; t < 4; t++) {
        int c = t * 16 + frow;
        asv[t] = att_s[c]; adv[t] = att_d[c];
    }
    int hb = (l >> 3) & 1;
    #pragma unroll
    for (int q = 0; q < 4; q++) {
        int n = nw + kg * 4 + q;
        #pragma unroll
        for (int t = 0; t < 4; t++) {
            float sv = acc[t][q] * asv[t];
            float dv = acc[t][q] * adv[t];
            sv += __shfl_xor(sv, 1); sv += __shfl_xor(sv, 2); sv += __shfl_xor(sv, 4);
            dv += __shfl_xor(dv, 1); dv += __shfl_xor(dv, 2); dv += __shfl_xor(dv, 4);
            if ((l & 7) == 0) {
                int h = t * 2 + hb;
                aad1[(size_t)n * 16 + h]     = sv;
                aad1[(size_t)n * 16 + 8 + h] = dv;
            }
        }
    }

    // h1 via LDS bounce -> coalesced 32B/lane stores
    __syncthreads();
    unsigned short* Hw = (unsigned short*)X + w * 1152;    // per-wave [16][72] bf16
    #pragma unroll
    for (int t = 0; t < 4; t++)
        #pragma unroll
        for (int q = 0; q < 4; q++)
            Hw[(kg * 4 + q) * 72 + t * 16 + frow] = f2bf(acc[t][q]);
    int rr = l >> 2, cc = l & 3;
    int n2 = nw + rr;
    unsigned short* dst = (unsigned short*)h1b + (size_t)n2 * 64 + cc * 16;
    *(uint4*)dst       = *(const uint4*)&Hw[rr * 72 + cc * 16];
    *(uint4*)(dst + 8) = *(const uint4*)&Hw[rr * 72 + cc * 16 + 8];
}

// ---------------- per-edge softmax numerators (bf16) ----------------

__global__ __launch_bounds__(256) void k_edgew(const float* aad, const int* col, const int* rowv,
                                               __hip_bfloat16* web) {
    int e = blockIdx.x * 256 + threadIdx.x;
    if (e >= NT) return;
    int s = col[e], d = rowv[e];
    float4 s0 = *(const float4*)&aad[(size_t)s * 16];
    float4 s1 = *(const float4*)&aad[(size_t)s * 16 + 4];
    float4 dd0 = *(const float4*)&aad[(size_t)d * 16 + 8];
    float4 dd1 = *(const float4*)&aad[(size_t)d * 16 + 12];
    float as[8] = {s0.x, s0.y, s0.z, s0.w, s1.x, s1.y, s1.z, s1.w};
    float ad[8] = {dd0.x, dd0.y, dd0.z, dd0.w, dd1.x, dd1.y, dd1.z, dd1.w};
    unsigned p[4];
    #pragma unroll
    for (int q = 0; q < 4; q++) {
        float a0 = as[2*q]   + ad[2*q];
        float a1 = as[2*q+1] + ad[2*q+1];
        a0 = a0 > 0.f ? a0 : 0.2f * a0;
        a1 = a1 > 0.f ? a1 : 0.2f * a1;
        p[q] = (unsigned)f2bf(__expf(a0)) | ((unsigned)f2bf(__expf(a1)) << 16);
    }
    *(uint4*)&web[(size_t)e * 8] = make_uint4(p[0], p[1], p[2], p[3]);
}

// ---------------- Layer-1 aggregation + att2 fused: 8 lanes/node (uint4 gathers) ----------------
// Lane q8 owns channel octet q8*8..+7 == exactly head q8 -> needs only weight w[q8].

__global__ __launch_bounds__(256) void k_agg1f(const __hip_bfloat16* h1b, const __hip_bfloat16* we1b,
                                               const int* rowptr, const int* col,
                                               const float* b1, const float* wsd,
                                               __hip_bfloat16* out1b, float* aad2) {
    int tid = threadIdx.x;
    int q8 = tid & 7;                          // channel octet == head
    int n = blockIdx.x * 32 + (tid >> 3);      // NN = 32*3125 exact
    const unsigned short* h1u = (const unsigned short*)h1b;
    const unsigned short* weu = (const unsigned short*)we1b;
    int rs = rowptr[n], re = rowptr[n + 1];
    float acc[8] = {};
    float den = 0.f;
    for (int eb = rs; eb < re; eb += 4) {
        int c4[4];
        #pragma unroll
        for (int j = 0; j < 4; j++) c4[j] = col[min(eb + j, re - 1)];   // batched col loads
        #pragma unroll
        for (int j = 0; j < 4; j++) {
            int e = min(eb + j, re - 1);
            float w = bfu(weu[(size_t)e * 8 + q8]);                     // head q8 weight
            w = (eb + j < re) ? w : 0.f;                                // predicate after load
            uint4 hv = *(const uint4*)&h1u[(size_t)c4[j] * 64 + q8 * 8];
            den += w;
            acc[0] += w * bfu((unsigned short)(hv.x & 0xffff));
            acc[1] += w * bfu((unsigned short)(hv.x >> 16));
            acc[2] += w * bfu((unsigned short)(hv.y & 0xffff));
            acc[3] += w * bfu((unsigned short)(hv.y >> 16));
            acc[4] += w * bfu((unsigned short)(hv.z & 0xffff));
            acc[5] += w * bfu((unsigned short)(hv.z >> 16));
            acc[6] += w * bfu((unsigned short)(hv.w & 0xffff));
            acc[7] += w * bfu((unsigned short)(hv.w >> 16));
        }
    }
    float inv = 1.0f / (den + 1e-16f);
    float4 b0 = *(const float4*)&b1[q8 * 8];
    float4 b4 = *(const float4*)&b1[q8 * 8 + 4];
    float bb[8] = {b0.x, b0.y, b0.z, b0.w, b4.x, b4.y, b4.z, b4.w};
    unsigned short u[8];
    float r[8];
    #pragma unroll
    for (int k = 0; k < 8; k++) {
        u[k] = f2bf(acc[k] * inv + bb[k]);
        r[k] = bfu(u[k]);                      // the rounded value att2 consumed before
    }
    unsigned short* ou = (unsigned short*)out1b;
    uint4 pk;
    pk.x = (unsigned)u[0] | ((unsigned)u[1] << 16);
    pk.y = (unsigned)u[2] | ((unsigned)u[3] << 16);
    pk.z = (unsigned)u[4] | ((unsigned)u[5] << 16);
    pk.w = (unsigned)u[6] | ((unsigned)u[7] << 16);
    *(uint4*)&ou[(size_t)n * 64 + q8 * 8] = pk;

    // fused att2: p[j] = <out1[n], wsd[j]>, 8-lane butterfly within the node octet
    float p[16];
    #pragma unroll
    for (int j = 0; j < 16; j++) {
        float4 w0 = *(const float4*)&wsd[j * 64 + q8 * 8];
        float4 w4 = *(const float4*)&wsd[j * 64 + q8 * 8 + 4];
        p[j] = r[0] * w0.x + r[1] * w0.y + r[2] * w0.z + r[3] * w0.w
             + r[4] * w4.x + r[5] * w4.y + r[6] * w4.z + r[7] * w4.w;
    }
    #pragma unroll
    for (int s = 1; s < 8; s <<= 1)
        #pragma unroll
        for (int j = 0; j < 16; j++) p[j] += __shfl_xor(p[j], s);
    float p0 = 0.f, p1 = 0.f;
    #pragma unroll
    for (int j = 0; j < 8; j++) {
        p0 = (q8 == j) ? p[j] : p0;
        p1 = (q8 == j) ? p[8 + j] : p1;
    }
    aad2[(size_t)n * 16 + q8]     = p0;
    aad2[(size_t)n * 16 + 8 + q8] = p1;
}

// ---------------- FUSED layer-2: agg2 + gemm2 + mlp heads + CE + final, r9 structure ----------------
// Phase A: 8 lanes/node (uint4 gathers, broadcast uint4 weights), 2 passes of 32 nodes,
//          acc[8 heads][8 ch] per lane, swizzled uint4 stores to Ax. (r9, measured 74.5 us)
// Phases B/C/D: r9 structure. Final loss via device atomics (last block writes out).

__global__ __launch_bounds__(256) void k_l2f(const __hip_bfloat16* out1b, const __hip_bfloat16* we2b,
                                             const int* rowptr, const int* col,
                                             const __hip_bfloat16* W2pT, const float* b2,
                                             const __hip_bfloat16* wB,
                                             const float* tsb1, const float* cb1,
                                             const float* tsw2, const float* tsb2,
                                             const float* cw2, const float* cb2,
                                             const int* tst, const int* ctg, const unsigned char* msk,
                                             float* acc3, int* cnt1, float* out) {
    __shared__ unsigned short Ax[64 * 512];    // 64 KB agg tile (swizzled); front reused as o2L
    __shared__ unsigned short Bl[64 * 72];     // 9.2 KB B stage
    __shared__ float red[4][3];
    int tid = threadIdx.x;
    int l = tid & 63, w = tid >> 6;
    int n0 = blockIdx.x * 64;
    int frow = l & 15, kg = l >> 4;

    // ---- phase A: 8 lanes/node, 2 passes of 32 nodes ----
    const unsigned short* o1u = (const unsigned short*)out1b;
    const unsigned short* weu = (const unsigned short*)we2b;
    int q8 = tid & 7;
    #pragma unroll 1
    for (int pass = 0; pass < 2; pass++) {
        int j = pass * 32 + (tid >> 3);        // node-local [0,64)
        int n = n0 + j;
        int rs = 0, re = 0;
        if (n < NN) { rs = rowptr[n]; re = rowptr[n + 1]; }
        float acc[8][8];
        float den[8];
        #pragma unroll
        for (int h = 0; h < 8; h++) {
            den[h] = 0.f;
            #pragma unroll
            for (int c = 0; c < 8; c++) acc[h][c] = 0.f;
        }
        for (int eb = rs; eb < re; eb += 4) {
            int c4[4];
            #pragma unroll
            for (int jj = 0; jj < 4; jj++) c4[jj] = col[min(eb + jj, re - 1)];
            #pragma unroll
            for (int jj = 0; jj < 4; jj++) {
                int e = min(eb + jj, re - 1);
                uint4 wv = *(const uint4*)&weu[(size_t)e * 8];           // uniform -> broadcast
                uint4 hv = *(const uint4*)&o1u[(size_t)c4[jj] * 64 + q8 * 8];
                float vm = (eb + jj < re) ? 1.f : 0.f;
                float hc[8] = {bfu((unsigned short)(hv.x & 0xffff)), bfu((unsigned short)(hv.x >> 16)),
                               bfu((unsigned short)(hv.y & 0xffff)), bfu((unsigned short)(hv.y >> 16)),
                               bfu((unsigned short)(hv.z & 0xffff)), bfu((unsigned short)(hv.z >> 16)),
                               bfu((unsigned short)(hv.w & 0xffff)), bfu((unsigned short)(hv.w >> 16))};
                float wt[8] = {bfu((unsigned short)(wv.x & 0xffff)), bfu((unsigned short)(wv.x >> 16)),
                               bfu((unsigned short)(wv.y & 0xffff)), bfu((unsigned short)(wv.y >> 16)),
                               bfu((unsigned short)(wv.z & 0xffff)), bfu((unsigned short)(wv.z >> 16)),
                               bfu((unsigned short)(wv.w & 0xffff)), bfu((unsigned short)(wv.w >> 16))};
                #pragma unroll
                for (int h = 0; h < 8; h++) {
                    float ww = wt[h] * vm;
                    den[h] += ww;
                    #pragma unroll
                    for (int c = 0; c < 8; c++) acc[h][c] += ww * hc[c];
                }
            }
        }
        unsigned short* row = &Ax[j * 512];
        #pragma unroll
        for (int h = 0; h < 8; h++) {
            float inv = 1.0f / (den[h] + 1e-16f);
            uint4 pk;
            pk.x = (unsigned)f2bf(acc[h][0] * inv) | ((unsigned)f2bf(acc[h][1] * inv) << 16);
            pk.y = (unsigned)f2bf(acc[h][2] * inv) | ((unsigned)f2bf(acc[h][3] * inv) << 16);
            pk.z = (unsigned)f2bf(acc[h][4] * inv) | ((unsigned)f2bf(acc[h][5] * inv) << 16);
            pk.w = (unsigned)f2bf(acc[h][6] * inv) | ((unsigned)f2bf(acc[h][7] * inv) << 16);
            int blk = (h * 8 + q8) ^ (j & 7);                           // 16B-block swizzle
            *(uint4*)&row[blk * 8] = pk;
        }
    }
    __syncthreads();

    // ---- phase B: gemm2 MFMA (rows = nodes, cols = 64 out ch, K = 512) ----
    const unsigned short* B_g = (const unsigned short*)W2pT;
    f32x4_t gacc[4] = {};
    #pragma unroll 1
    for (int k0 = 0; k0 < 512; k0 += 64) {
        #pragma unroll
        for (int ll = 0; ll < 2; ll++) {
            int u = tid + ll * 256;            // [0,512): r = out col, seg = 8x8 bf16
            int r = u >> 3, seg = u & 7;
            *(uint4*)&Bl[r * 72 + seg * 8] = *(const uint4*)&B_g[(size_t)r * 512 + k0 + seg * 8];
        }
        __syncthreads();
        #pragma unroll
        for (int kk = 0; kk < 2; kk++) {
            int blk = ((k0 >> 3) + kk * 4 + kg) ^ (frow & 7);
            bf16x8_t a = *(const bf16x8_t*)&Ax[(w * 16 + frow) * 512 + blk * 8];
            #pragma unroll
            for (int t = 0; t < 4; t++) {
                bf16x8_t bb = *(const bf16x8_t*)&Bl[(t * 16 + frow) * 72 + kk * 32 + kg * 8];
                gacc[t] = __builtin_amdgcn_mfma_f32_16x16x32_bf16(a, bb, gacc[t], 0, 0, 0);
            }
        }
        __syncthreads();
    }

    // ---- phase C: o2 bf16 -> LDS (reuse Ax front), then mlp1 MFMA vs wB ----
    unsigned short* o2L = Ax;                  // [64][72] bf16
    #pragma unroll
    for (int t = 0; t < 4; t++) {
        float bias = b2[t * 16 + frow];
        #pragma unroll
        for (int q = 0; q < 4; q++)
            o2L[(w * 16 + kg * 4 + q) * 72 + t * 16 + frow] = f2bf(0.125f * gacc[t][q] + bias);
    }
    __syncthreads();
    const unsigned short* wBu = (const unsigned short*)wB;
    f32x4_t a2c[8] = {};
    #pragma unroll
    for (int kk = 0; kk < 2; kk++) {
        bf16x8_t a2 = *(const bf16x8_t*)&o2L[(w * 16 + frow) * 72 + kk * 32 + kg * 8];
        #pragma unroll
        for (int t2 = 0; t2 < 8; t2++) {
            bf16x8_t b2f = *(const bf16x8_t*)&wBu[(t2 * 16 + frow) * 64 + kk * 32 + kg * 8];
            a2c[t2] = __builtin_amdgcn_mfma_f32_16x16x32_bf16(a2, b2f, a2c[t2], 0, 0, 0);
        }
    }

    // ---- phase D: bias+relu+second-layer projections, reduce, CE ----
    float lg[4][5]; float lc[4][2];
    #pragma unroll
    for (int q = 0; q < 4; q++) {
        #pragma unroll
        for (int t = 0; t < 5; t++) lg[q][t] = 0.f;
        lc[q][0] = 0.f; lc[q][1] = 0.f;
    }
    #pragma unroll
    for (int t2 = 0; t2 < 4; t2++) {
        int c = t2 * 16 + frow;
        float bb = tsb1[c];
        float w0 = tsw2[c * 5 + 0], w1 = tsw2[c * 5 + 1], w2 = tsw2[c * 5 + 2],
              w3 = tsw2[c * 5 + 3], w4 = tsw2[c * 5 + 4];
        #pragma unroll
        for (int q = 0; q < 4; q++) {
            float v = fmaxf(a2c[t2][q] + bb, 0.f);
            lg[q][0] += v * w0; lg[q][1] += v * w1; lg[q][2] += v * w2;
            lg[q][3] += v * w3; lg[q][4] += v * w4;
        }
    }
    #pragma unroll
    for (int t2 = 0; t2 < 4; t2++) {
        int c = t2 * 16 + frow;
        float bb = cb1[c];
        float u0 = cw2[c * 2], u1 = cw2[c * 2 + 1];
        #pragma unroll
        for (int q = 0; q < 4; q++) {
            float v = fmaxf(a2c[t2 + 4][q] + bb, 0.f);
            lc[q][0] += v * u0; lc[q][1] += v * u1;
        }
    }
    #pragma unroll
    for (int q = 0; q < 4; q++) {
        #pragma unroll
        for (int t = 0; t < 5; t++) {
            lg[q][t] += __shfl_xor(lg[q][t], 1);
            lg[q][t] += __shfl_xor(lg[q][t], 2);
            lg[q][t] += __shfl_xor(lg[q][t], 4);
            lg[q][t] += __shfl_xor(lg[q][t], 8);
        }
        #pragma unroll
        for (int t = 0; t < 2; t++) {
            lc[q][t] += __shfl_xor(lc[q][t], 1);
            lc[q][t] += __shfl_xor(lc[q][t], 2);
            lc[q][t] += __shfl_xor(lc[q][t], 4);
            lc[q][t] += __shfl_xor(lc[q][t], 8);
        }
    }
    float tsl = 0.f, cll = 0.f, mval = 0.f;
    if (frow == 0) {
        #pragma unroll
        for (int q = 0; q < 4; q++) {
            int n = n0 + w * 16 + kg * 4 + q;
            if (n < NN) {
                float L[5];
                #pragma unroll
                for (int t = 0; t < 5; t++) L[t] = lg[q][t] + tsb2[t];
                float mx = fmaxf(fmaxf(fmaxf(L[0], L[1]), fmaxf(L[2], L[3])), L[4]);
                float se = 0.f;
                #pragma unroll
                for (int t = 0; t < 5; t++) se += __expf(L[t] - mx);
                int tg = tst[n];
                float pick = 0.f;
                #pragma unroll
                for (int t = 0; t < 5; t++) pick += (t == tg) ? L[t] : 0.f;
                tsl += mx + __logf(se) - pick;
                float C0 = lc[q][0] + cb2[0];
                float C1 = lc[q][1] + cb2[1];
                float mx2 = fmaxf(C0, C1);
                float lse2 = mx2 + __logf(__expf(C0 - mx2) + __expf(C1 - mx2));
                float mv = msk[n] ? 1.f : 0.f;
                float pick2 = ctg[n] ? C1 : C0;
                cll += (lse2 - pick2) * mv;
                mval += mv;
            }
        }
    }
    #pragma unroll
    for (int off = 1; off < 64; off <<= 1) {
        tsl  += __shfl_xor(tsl, off);
        cll  += __shfl_xor(cll, off);
        mval += __shfl_xor(mval, off);
    }
    if (l == 0) { red[w][0] = tsl; red[w][1] = cll; red[w][2] = mval; }
    __syncthreads();
    if (tid == 0) {
        float s0 = red[0][0] + red[1][0] + red[2][0] + red[3][0];
        float s1 = red[0][1] + red[1][1] + red[2][1] + red[3][1];
        float s2 = red[0][2] + red[1][2] + red[2][2] + red[3][2];
        atomicAdd(&acc3[0], s0);
        atomicAdd(&acc3[1], s1);
        atomicAdd(&acc3[2], s2);
        __threadfence();
        int old = atomicAdd(cnt1, 1);
        if (old == NODEB - 1) {                // last block finalizes the loss
            float t0 = atomicAdd(&acc3[0], 0.f);
            float t1 = atomicAdd(&acc3[1], 0.f);
            float t2 = atomicAdd(&acc3[2], 0.f);
            out[0] = t1 / t2 + t0 / (float)NN;
        }
    }
}

// ---------------- host ----------------

extern "C" void kernel_launch(void* const* d_in, const int* in_sizes, int n_in,
                              void* d_out, int out_size, void* d_ws, size_t ws_size,
                              hipStream_t stream) {
    const float* x    = (const float*)d_in[0];
    const int*   ei   = (const int*)d_in[1];
    const int*   tst  = (const int*)d_in[2];
    const int*   ctg  = (const int*)d_in[3];
    const unsigned char* msk = (const unsigned char*)d_in[4];
    const float* W1   = (const float*)d_in[5];
    const float* a1s  = (const float*)d_in[6];
    const float* a1d  = (const float*)d_in[7];
    const float* b1   = (const float*)d_in[8];
    const float* W2   = (const float*)d_in[9];
    const float* a2s  = (const float*)d_in[10];
    const float* a2d  = (const float*)d_in[11];
    const float* b2   = (const float*)d_in[12];
    const float* tsw1 = (const float*)d_in[13];
    const float* tsb1 = (const float*)d_in[14];
    const float* tsw2 = (const float*)d_in[15];
    const float* tsb2 = (const float*)d_in[16];
    const float* cw1  = (const float*)d_in[17];
    const float* cb1  = (const float*)d_in[18];
    const float* cw2  = (const float*)d_in[19];
    const float* cb2  = (const float*)d_in[20];
    const int* srcE = ei;
    const int* dstE = ei + NE;

    char* ws = (char*)d_ws;
    size_t off = 0;
    auto alloc = [&](size_t b) { size_t o = off; off = (off + b + 255) & ~(size_t)255; return o; };
    int*   cnt    = (int*)(ws + alloc((size_t)NN * 4));
    int*   fill   = (int*)(ws + alloc((size_t)NN * 4));
    int*   rowptr = (int*)(ws + alloc((size_t)(NN + 1) * 4));
    int*   bsum   = (int*)(ws + alloc(128 * 4));
    int*   col    = (int*)(ws + alloc((size_t)NT * 4));
    int*   rowv   = (int*)(ws + alloc((size_t)NT * 4));
    float* aad1   = (float*)(ws + alloc((size_t)NN * 16 * 4));
    __hip_bfloat16* out1b = (__hip_bfloat16*)(ws + alloc((size_t)NN * 64 * 2));
    float* aad2   = (float*)(ws + alloc((size_t)NN * 16 * 4));
    float* wsd    = (float*)(ws + alloc(1024 * 4));
    __hip_bfloat16* W2pT  = (__hip_bfloat16*)(ws + alloc(32768 * 2));
    __hip_bfloat16* wB    = (__hip_bfloat16*)(ws + alloc(8192 * 2));
    unsigned* W1pT = (unsigned*)(ws + alloc(6144 * 4));
    float* zbuf   = (float*)(ws + alloc(256 * 4));
    __hip_bfloat16* h1b   = (__hip_bfloat16*)(ws + alloc((size_t)NN * 64 * 2));
    __hip_bfloat16* web   = (__hip_bfloat16*)(ws + alloc((size_t)NT * 8 * 2));
    float* acc3   = (float*)(ws + alloc(4 * 4));
    int*   cnt1   = (int*)(ws + alloc(4 * 4));
    (void)ws_size; (void)in_sizes; (void)n_in; (void)out_size;

    int nb_scan = (NN + 1023) / 1024;  // 98

    k_misc<<<MISCGRID, 256, 0, stream>>>(W2, a2s, a2d, wsd, W2pT, cnt, fill,
                                         tsw1, cw1, wB, W1, W1pT, zbuf, acc3, cnt1);
    k_count<<<(NE + 255) / 256, 256, 0, stream>>>(dstE, cnt);
    k_scanA<<<nb_scan, 256, 0, stream>>>(cnt, rowptr, bsum);
    k_scanC<<<(NN + 255) / 256, 256, 0, stream>>>(bsum, rowptr, nb_scan);
    k_fill<<<(NT + 255) / 256, 256, 0, stream>>>(srcE, dstE, rowptr, fill, col, rowv);

    k_gemm1<<<NN / G1ROWS, 128, 0, stream>>>(x, W1pT, a1s, a1d, zbuf, h1b, aad1);
    k_edgew<<<(NT + 255) / 256, 256, 0, stream>>>(aad1, col, rowv, web);
    k_agg1f<<<NN / 32, 256, 0, stream>>>(h1b, web, rowptr, col, b1, wsd, out1b, aad2);
    k_edgew<<<(NT + 255) / 256, 256, 0, stream>>>(aad2, col, rowv, web);

    k_l2f<<<NODEB, 256, 0, stream>>>(out1b, web, rowptr, col, W2pT, b2, wB,
                                     tsb1, cb1, tsw2, tsb2, cw2, cb2, tst, ctg, msk,
                                     acc3, cnt1, (float*)d_out);
}

// Round 13
// 176.809 us; speedup vs baseline: 1.4302x; 1.2118x over previous
//
#include <hip/hip_runtime.h>
#include <hip/hip_bf16.h>

#define NN 100000      // nodes
#define NE 200000      // edges (without self loops)
#define NT (NE + NN)   // total edges incl self loops
#define DIN 165
#define PREPB 128
#define INITB 391
#define PACKB 32       // 8192 threads: wB [128 cols][64 k] bf16 pack
#define W1PB 24        // W1 f16 [c][192] pack: 6144 u32
#define MISCGRID (PREPB + INITB + PACKB + W1PB)
#define NODEB 1563     // ceil(NN/64) blocks (64-node tiles)
#define XDW ((size_t)NN * DIN)   // total x dwords (16.5M, divisible by 4)
#define G1ROWS 32      // gemm1 rows/block (NN = 3125*32 exact)
#define G1NDMA 21      // 21 KiB staged per 32-row tile (need 21120B, have 21504B)

typedef __attribute__((ext_vector_type(8))) short bf16x8_t;
typedef __attribute__((ext_vector_type(4))) float f32x4_t;
typedef _Float16 h2_t __attribute__((ext_vector_type(2)));
typedef _Float16 f16x8_t __attribute__((ext_vector_type(8)));

#define AS1 __attribute__((address_space(1)))
#define AS3 __attribute__((address_space(3)))

static __device__ __forceinline__ unsigned short f2bf(float f) {
    __hip_bfloat16 b = __float2bfloat16(f);
    return *(unsigned short*)&b;
}
static __device__ __forceinline__ float bfu(unsigned short u) {
    __hip_bfloat16 b = *(__hip_bfloat16*)&u;
    return __bfloat162float(b);
}
static __device__ __forceinline__ unsigned pkh2(float a, float b) {
    h2_t v; v[0] = (_Float16)a; v[1] = (_Float16)b;
    return *(unsigned*)&v;
}

// ---------------- merged prep: W2pT/wsd | CSR init | mlp wB pack | W1 f16 pack ----------------

__global__ __launch_bounds__(256) void k_misc(const float* W2, const float* a2s, const float* a2d,
                                              float* wsd, __hip_bfloat16* W2pT,
                                              int* cnt, int* fill,
                                              const float* tsw1, const float* cw1,
                                              __hip_bfloat16* wB,
                                              const float* W1, unsigned* W1pT, float* zbuf) {
    int b = blockIdx.x;
    int tid = threadIdx.x;
    if (b < PREPB) {
        int i = b * 256 + tid;                 // [0, 32768)
        // W2pT[c][j] = bf16(W2[kk*512 + h*64 + c]),  j = h*64 + kk
        int c = i >> 9, j = i & 511;
        int hh = j >> 6, kk = j & 63;
        W2pT[i] = __float2bfloat16(W2[kk * 512 + hh * 64 + c]);
        if (b == 0) zbuf[tid] = 0.f;           // zero source for gemm1 DMA padding
        if (i < 512) {
            int h = i >> 6, k = i & 63;
            float s = 0.f, d = 0.f;
            for (int cc = 0; cc < 64; cc++) {
                float w = W2[k * 512 + h * 64 + cc];
                s += w * a2s[h * 64 + cc];
                d += w * a2d[h * 64 + cc];
            }
            wsd[i] = s; wsd[512 + i] = d;
        }
    } else if (b < PREPB + INITB) {
        int i = (b - PREPB) * 256 + tid;
        if (i < NN) { cnt[i] = 0; fill[i] = 0; }
    } else if (b < PREPB + INITB + PACKB) {
        int i = (b - PREPB - INITB) * 256 + tid;  // [0, 8192): c*64 + k
        if (i < 8192) {
            int c = i >> 6, k = i & 63;
            float v = (c < 64) ? tsw1[k * 64 + c] : cw1[k * 64 + (c - 64)];
            wB[i] = __float2bfloat16(v);          // [128 cols][64 k]: ts cols 0-63, cls 64-127
        }
    } else {
        int i = (b - PREPB - INITB - PACKB) * 256 + tid;  // [0, 6144): c*96 + kp
        if (i < 6144) {
            int c = i / 96, kp = i - c * 96;
            int k = 2 * kp;
            float f0 = (k < DIN) ? W1[k * 64 + c] : 0.f;
            float f1 = (k + 1 < DIN) ? W1[(k + 1) * 64 + c] : 0.f;
            W1pT[i] = pkh2(f0, f1);               // [c][96] u32 = [c][192] f16, zero-padded K
        }
    }
}

// ---------------- CSR build ----------------

__global__ __launch_bounds__(256) void k_count(const int* dstE, int* cnt) {
    int e = blockIdx.x * 256 + threadIdx.x;
    if (e < NE) atomicAdd(&cnt[dstE[e]], 1);
}

__global__ __launch_bounds__(256) void k_scanA(const int* cnt, int* rowptr, int* bsum) {
    __shared__ int sm[256];
    int t = threadIdx.x;
    int base = blockIdx.x * 1024;
    int v[4]; int s = 0;
    for (int i = 0; i < 4; i++) {
        int idx = base + t * 4 + i;
        v[i] = (idx < NN) ? (cnt[idx] + 1) : 0;
        s += v[i];
    }
    sm[t] = s; __syncthreads();
    for (int off = 1; off < 256; off <<= 1) {
        int x = (t >= off) ? sm[t - off] : 0;
        __syncthreads();
        sm[t] += x;
        __syncthreads();
    }
    int run = sm[t] - s;
    for (int i = 0; i < 4; i++) {
        run += v[i];
        int idx = base + t * 4 + i;
        if (idx < NN) rowptr[idx + 1] = run;
    }
    if (t == 255) bsum[blockIdx.x] = sm[255];
}

// scanC with folded scanB: each block re-derives the exclusive prefix of bsum (nb<=128) in-wave
__global__ __launch_bounds__(256) void k_scanC(const int* bsum, int* rowptr, int nb) {
    __shared__ int pre[128];
    int tid = threadIdx.x;
    if (tid < 64) {
        int lane = tid;
        int v0 = (lane < nb) ? bsum[lane] : 0;
        int v1 = (64 + lane < nb) ? bsum[64 + lane] : 0;
        int s0 = v0;
        for (int off = 1; off < 64; off <<= 1) { int t = __shfl_up(s0, off); if (lane >= off) s0 += t; }
        int tot0 = __shfl(s0, 63);
        int s1 = v1;
        for (int off = 1; off < 64; off <<= 1) { int t = __shfl_up(s1, off); if (lane >= off) s1 += t; }
        pre[lane] = s0 - v0;
        pre[64 + lane] = tot0 + s1 - v1;
    }
    __syncthreads();
    int i = blockIdx.x * 256 + tid;
    if (i < NN) rowptr[i + 1] += pre[i >> 10];
    if (i == 0) rowptr[0] = 0;
}

__global__ __launch_bounds__(256) void k_fill(const int* srcE, const int* dstE,
                                              const int* rowptr, int* fill, int* col, int* rowv) {
    int i = blockIdx.x * 256 + threadIdx.x;
    if (i >= NT) return;
    int s, d;
    if (i < NE) { s = srcE[i]; d = dstE[i]; }
    else        { s = i - NE; d = s; }        // self loop
    int p = rowptr[d] + atomicAdd(&fill[d], 1);
    col[p] = s;
    rowv[p] = d;
}

// ---------------- Layer 1 GEMM (f16 MFMA): 32-row tiles, 128 thr, burst DMA ----------------

__global__ __launch_bounds__(128) void k_gemm1(const float* x, const unsigned* W1pT,
                                               const float* att_s, const float* att_d,
                                               const float* zsrc,
                                               __hip_bfloat16* h1b, float* aad1) {
    __shared__ float X[G1NDMA * 256];          // 21504 B staged tile; reused as h1 bounce
    int tid = threadIdx.x;
    int l = tid & 63, w = tid >> 6;            // w in {0,1}
    int n0 = blockIdx.x * G1ROWS;
    int frow = l & 15, kg = l >> 4;

    // burst-stage whole 32x165 f32 tile (contiguous, 16B-aligned: n0*660B)
    size_t tb = (size_t)n0 * DIN;
    for (int i = w; i < G1NDMA; i += 2) {
        size_t gd = tb + (size_t)i * 256 + (size_t)l * 4;
        const float* g = (gd + 4 <= XDW) ? (x + gd) : (zsrc + l * 4);
        __builtin_amdgcn_global_load_lds((const AS1 float*)g,
                                         (AS3 float*)(X + i * 256), 16, 0, 0);
    }
    // preload ALL B fragments (24 KB W1pT, L2-resident) while DMA flies
    uint4 B[6][4];
    #pragma unroll
    for (int s = 0; s < 6; s++)
        #pragma unroll
        for (int t = 0; t < 4; t++)
            B[s][t] = *(const uint4*)&W1pT[(t * 16 + frow) * 96 + s * 16 + kg * 4];
    __syncthreads();                           // drains vmcnt: tile + B ready

    // 6 MFMA steps, all operands local (over-read past k=165 annihilated by W1pT zero-pad)
    f32x4_t acc[4] = {};
    int rbase = (w * 16 + frow) * DIN + kg * 8;
    #pragma unroll
    for (int s = 0; s < 6; s++) {
        f16x8_t av;
        #pragma unroll
        for (int j = 0; j < 8; j++) av[j] = (_Float16)X[rbase + s * 32 + j];
        #pragma unroll
        for (int t = 0; t < 4; t++)
            acc[t] = __builtin_amdgcn_mfma_f32_16x16x32_f16(av, *(f16x8_t*)&B[s][t], acc[t], 0, 0, 0);
    }

    // attention partials (C/D: col=l&15 -> c=t*16+frow, row=kg*4+q [m89])
    int nw = n0 + w * 16;
    float asv[4], adv[4];
    #pragma unroll
    for (int t = 0; t < 4; t++) {
        int c = t * 16 + frow;
        asv[t] = att_s[c]; adv[t] = att_d[c];
    }
    int hb = (l >> 3) & 1;
    #pragma unroll
    for (int q = 0; q < 4; q++) {
        int n = nw + kg * 4 + q;
        #pragma unroll
        for (int t = 0; t < 4; t++) {
            float sv = acc[t][q] * asv[t];
            float dv = acc[t][q] * adv[t];
            sv += __shfl_xor(sv, 1); sv += __shfl_xor(sv, 2); sv += __shfl_xor(sv, 4);
            dv += __shfl_xor(dv, 1); dv += __shfl_xor(dv, 2); dv += __shfl_xor(dv, 4);
            if ((l & 7) == 0) {
                int h = t * 2 + hb;
                aad1[(size_t)n * 16 + h]     = sv;
                aad1[(size_t)n * 16 + 8 + h] = dv;
            }
        }
    }

    // h1 via LDS bounce -> coalesced 32B/lane stores
    __syncthreads();
    unsigned short* Hw = (unsigned short*)X + w * 1152;    // per-wave [16][72] bf16
    #pragma unroll
    for (int t = 0; t < 4; t++)
        #pragma unroll
        for (int q = 0; q < 4; q++)
            Hw[(kg * 4 + q) * 72 + t * 16 + frow] = f2bf(acc[t][q]);
    int rr = l >> 2, cc = l & 3;
    int n2 = nw + rr;
    unsigned short* dst = (unsigned short*)h1b + (size_t)n2 * 64 + cc * 16;
    *(uint4*)dst       = *(const uint4*)&Hw[rr * 72 + cc * 16];
    *(uint4*)(dst + 8) = *(const uint4*)&Hw[rr * 72 + cc * 16 + 8];
}

// ---------------- per-edge softmax numerators (bf16) ----------------

__global__ __launch_bounds__(256) void k_edgew(const float* aad, const int* col, const int* rowv,
                                               __hip_bfloat16* web) {
    int e = blockIdx.x * 256 + threadIdx.x;
    if (e >= NT) return;
    int s = col[e], d = rowv[e];
    float4 s0 = *(const float4*)&aad[(size_t)s * 16];
    float4 s1 = *(const float4*)&aad[(size_t)s * 16 + 4];
    float4 dd0 = *(const float4*)&aad[(size_t)d * 16 + 8];
    float4 dd1 = *(const float4*)&aad[(size_t)d * 16 + 12];
    float as[8] = {s0.x, s0.y, s0.z, s0.w, s1.x, s1.y, s1.z, s1.w};
    float ad[8] = {dd0.x, dd0.y, dd0.z, dd0.w, dd1.x, dd1.y, dd1.z, dd1.w};
    unsigned p[4];
    #pragma unroll
    for (int q = 0; q < 4; q++) {
        float a0 = as[2*q]   + ad[2*q];
        float a1 = as[2*q+1] + ad[2*q+1];
        a0 = a0 > 0.f ? a0 : 0.2f * a0;
        a1 = a1 > 0.f ? a1 : 0.2f * a1;
        p[q] = (unsigned)f2bf(__expf(a0)) | ((unsigned)f2bf(__expf(a1)) << 16);
    }
    *(uint4*)&web[(size_t)e * 8] = make_uint4(p[0], p[1], p[2], p[3]);
}

// ---------------- Layer-1 aggregation + att2 fused: 8 lanes/node (uint4 gathers) ----------------
// Lane q8 owns channel octet q8*8..+7 == exactly head q8 -> needs only weight w[q8].

__global__ __launch_bounds__(256) void k_agg1f(const __hip_bfloat16* h1b, const __hip_bfloat16* we1b,
                                               const int* rowptr, const int* col,
                                               const float* b1, const float* wsd,
                                               __hip_bfloat16* out1b, float* aad2) {
    int tid = threadIdx.x;
    int q8 = tid & 7;                          // channel octet == head
    int n = blockIdx.x * 32 + (tid >> 3);      // NN = 32*3125 exact
    const unsigned short* h1u = (const unsigned short*)h1b;
    const unsigned short* weu = (const unsigned short*)we1b;
    int rs = rowptr[n], re = rowptr[n + 1];
    float acc[8] = {};
    float den = 0.f;
    for (int eb = rs; eb < re; eb += 4) {
        int c4[4];
        #pragma unroll
        for (int j = 0; j < 4; j++) c4[j] = col[min(eb + j, re - 1)];   // batched col loads
        #pragma unroll
        for (int j = 0; j < 4; j++) {
            int e = min(eb + j, re - 1);
            float w = bfu(weu[(size_t)e * 8 + q8]);                     // head q8 weight
            w = (eb + j < re) ? w : 0.f;                                // predicate after load
            uint4 hv = *(const uint4*)&h1u[(size_t)c4[j] * 64 + q8 * 8];
            den += w;
            acc[0] += w * bfu((unsigned short)(hv.x & 0xffff));
            acc[1] += w * bfu((unsigned short)(hv.x >> 16));
            acc[2] += w * bfu((unsigned short)(hv.y & 0xffff));
            acc[3] += w * bfu((unsigned short)(hv.y >> 16));
            acc[4] += w * bfu((unsigned short)(hv.z & 0xffff));
            acc[5] += w * bfu((unsigned short)(hv.z >> 16));
            acc[6] += w * bfu((unsigned short)(hv.w & 0xffff));
            acc[7] += w * bfu((unsigned short)(hv.w >> 16));
        }
    }
    float inv = 1.0f / (den + 1e-16f);
    float4 b0 = *(const float4*)&b1[q8 * 8];
    float4 b4 = *(const float4*)&b1[q8 * 8 + 4];
    float bb[8] = {b0.x, b0.y, b0.z, b0.w, b4.x, b4.y, b4.z, b4.w};
    unsigned short u[8];
    float r[8];
    #pragma unroll
    for (int k = 0; k < 8; k++) {
        u[k] = f2bf(acc[k] * inv + bb[k]);
        r[k] = bfu(u[k]);                      // the rounded value att2 consumed before
    }
    unsigned short* ou = (unsigned short*)out1b;
    uint4 pk;
    pk.x = (unsigned)u[0] | ((unsigned)u[1] << 16);
    pk.y = (unsigned)u[2] | ((unsigned)u[3] << 16);
    pk.z = (unsigned)u[4] | ((unsigned)u[5] << 16);
    pk.w = (unsigned)u[6] | ((unsigned)u[7] << 16);
    *(uint4*)&ou[(size_t)n * 64 + q8 * 8] = pk;

    // fused att2: p[j] = <out1[n], wsd[j]>, 8-lane butterfly within the node octet
    float p[16];
    #pragma unroll
    for (int j = 0; j < 16; j++) {
        float4 w0 = *(const float4*)&wsd[j * 64 + q8 * 8];
        float4 w4 = *(const float4*)&wsd[j * 64 + q8 * 8 + 4];
        p[j] = r[0] * w0.x + r[1] * w0.y + r[2] * w0.z + r[3] * w0.w
             + r[4] * w4.x + r[5] * w4.y + r[6] * w4.z + r[7] * w4.w;
    }
    #pragma unroll
    for (int s = 1; s < 8; s <<= 1)
        #pragma unroll
        for (int j = 0; j < 16; j++) p[j] += __shfl_xor(p[j], s);
    float p0 = 0.f, p1 = 0.f;
    #pragma unroll
    for (int j = 0; j < 8; j++) {
        p0 = (q8 == j) ? p[j] : p0;
        p1 = (q8 == j) ? p[8 + j] : p1;
    }
    aad2[(size_t)n * 16 + q8]     = p0;
    aad2[(size_t)n * 16 + 8 + q8] = p1;
}

// ---------------- FUSED layer-2: agg2 + gemm2 + mlp heads + CE (r9 structure, part[] tail) ----------------
// Phase A: 8 lanes/node (uint4 gathers, broadcast uint4 weights), 2 passes of 32 nodes,
//          acc[8 heads][8 ch] per lane, swizzled uint4 stores to Ax. (r9, measured 74.5 us)
// NOTE: no device-fence/atomic tail — that cost ~40 us (r12 lesson). part[] + separate k_final.

__global__ __launch_bounds__(256) void k_l2f(const __hip_bfloat16* out1b, const __hip_bfloat16* we2b,
                                             const int* rowptr, const int* col,
                                             const __hip_bfloat16* W2pT, const float* b2,
                                             const __hip_bfloat16* wB,
                                             const float* tsb1, const float* cb1,
                                             const float* tsw2, const float* tsb2,
                                             const float* cw2, const float* cb2,
                                             const int* tst, const int* ctg, const unsigned char* msk,
                                             float* part) {
    __shared__ unsigned short Ax[64 * 512];    // 64 KB agg tile (swizzled); front reused as o2L
    __shared__ unsigned short Bl[64 * 72];     // 9.2 KB B stage
    __shared__ float red[4][3];
    int tid = threadIdx.x;
    int l = tid & 63, w = tid >> 6;
    int n0 = blockIdx.x * 64;
    int frow = l & 15, kg = l >> 4;

    // ---- phase A: 8 lanes/node, 2 passes of 32 nodes ----
    const unsigned short* o1u = (const unsigned short*)out1b;
    const unsigned short* weu = (const unsigned short*)we2b;
    int q8 = tid & 7;
    #pragma unroll 1
    for (int pass = 0; pass < 2; pass++) {
        int j = pass * 32 + (tid >> 3);        // node-local [0,64)
        int n = n0 + j;
        int rs = 0, re = 0;
        if (n < NN) { rs = rowptr[n]; re = rowptr[n + 1]; }
        float acc[8][8];
        float den[8];
        #pragma unroll
        for (int h = 0; h < 8; h++) {
            den[h] = 0.f;
            #pragma unroll
            for (int c = 0; c < 8; c++) acc[h][c] = 0.f;
        }
        for (int eb = rs; eb < re; eb += 4) {
            int c4[4];
            #pragma unroll
            for (int jj = 0; jj < 4; jj++) c4[jj] = col[min(eb + jj, re - 1)];
            #pragma unroll
            for (int jj = 0; jj < 4; jj++) {
                int e = min(eb + jj, re - 1);
                uint4 wv = *(const uint4*)&weu[(size_t)e * 8];           // uniform -> broadcast
                uint4 hv = *(const uint4*)&o1u[(size_t)c4[jj] * 64 + q8 * 8];
                float vm = (eb + jj < re) ? 1.f : 0.f;
                float hc[8] = {bfu((unsigned short)(hv.x & 0xffff)), bfu((unsigned short)(hv.x >> 16)),
                               bfu((unsigned short)(hv.y & 0xffff)), bfu((unsigned short)(hv.y >> 16)),
                               bfu((unsigned short)(hv.z & 0xffff)), bfu((unsigned short)(hv.z >> 16)),
                               bfu((unsigned short)(hv.w & 0xffff)), bfu((unsigned short)(hv.w >> 16))};
                float wt[8] = {bfu((unsigned short)(wv.x & 0xffff)), bfu((unsigned short)(wv.x >> 16)),
                               bfu((unsigned short)(wv.y & 0xffff)), bfu((unsigned short)(wv.y >> 16)),
                               bfu((unsigned short)(wv.z & 0xffff)), bfu((unsigned short)(wv.z >> 16)),
                               bfu((unsigned short)(wv.w & 0xffff)), bfu((unsigned short)(wv.w >> 16))};
                #pragma unroll
                for (int h = 0; h < 8; h++) {
                    float ww = wt[h] * vm;
                    den[h] += ww;
                    #pragma unroll
                    for (int c = 0; c < 8; c++) acc[h][c] += ww * hc[c];
                }
            }
        }
        unsigned short* row = &Ax[j * 512];
        #pragma unroll
        for (int h = 0; h < 8; h++) {
            float inv = 1.0f / (den[h] + 1e-16f);
            uint4 pk;
            pk.x = (unsigned)f2bf(acc[h][0] * inv) | ((unsigned)f2bf(acc[h][1] * inv) << 16);
            pk.y = (unsigned)f2bf(acc[h][2] * inv) | ((unsigned)f2bf(acc[h][3] * inv) << 16);
            pk.z = (unsigned)f2bf(acc[h][4] * inv) | ((unsigned)f2bf(acc[h][5] * inv) << 16);
            pk.w = (unsigned)f2bf(acc[h][6] * inv) | ((unsigned)f2bf(acc[h][7] * inv) << 16);
            int blk = (h * 8 + q8) ^ (j & 7);                           // 16B-block swizzle
            *(uint4*)&row[blk * 8] = pk;
        }
    }
    __syncthreads();

    // ---- phase B: gemm2 MFMA (rows = nodes, cols = 64 out ch, K = 512) ----
    const unsigned short* B_g = (const unsigned short*)W2pT;
    f32x4_t gacc[4] = {};
    #pragma unroll 1
    for (int k0 = 0; k0 < 512; k0 += 64) {
        #pragma unroll
        for (int ll = 0; ll < 2; ll++) {
            int u = tid + ll * 256;            // [0,512): r = out col, seg = 8x8 bf16
            int r = u >> 3, seg = u & 7;
            *(uint4*)&Bl[r * 72 + seg * 8] = *(const uint4*)&B_g[(size_t)r * 512 + k0 + seg * 8];
        }
        __syncthreads();
        #pragma unroll
        for (int kk = 0; kk < 2; kk++) {
            int blk = ((k0 >> 3) + kk * 4 + kg) ^ (frow & 7);
            bf16x8_t a = *(const bf16x8_t*)&Ax[(w * 16 + frow) * 512 + blk * 8];
            #pragma unroll
            for (int t = 0; t < 4; t++) {
                bf16x8_t bb = *(const bf16x8_t*)&Bl[(t * 16 + frow) * 72 + kk * 32 + kg * 8];
                gacc[t] = __builtin_amdgcn_mfma_f32_16x16x32_bf16(a, bb, gacc[t], 0, 0, 0);
            }
        }
        __syncthreads();
    }

    // ---- phase C: o2 bf16 -> LDS (reuse Ax front), then mlp1 MFMA vs wB ----
    unsigned short* o2L = Ax;                  // [64][72] bf16
    #pragma unroll
    for (int t = 0; t < 4; t++) {
        float bias = b2[t * 16 + frow];
        #pragma unroll
        for (int q = 0; q < 4; q++)
            o2L[(w * 16 + kg * 4 + q) * 72 + t * 16 + frow] = f2bf(0.125f * gacc[t][q] + bias);
    }
    __syncthreads();
    const unsigned short* wBu = (const unsigned short*)wB;
    f32x4_t a2c[8] = {};
    #pragma unroll
    for (int kk = 0; kk < 2; kk++) {
        bf16x8_t a2 = *(const bf16x8_t*)&o2L[(w * 16 + frow) * 72 + kk * 32 + kg * 8];
        #pragma unroll
        for (int t2 = 0; t2 < 8; t2++) {
            bf16x8_t b2f = *(const bf16x8_t*)&wBu[(t2 * 16 + frow) * 64 + kk * 32 + kg * 8];
            a2c[t2] = __builtin_amdgcn_mfma_f32_16x16x32_bf16(a2, b2f, a2c[t2], 0, 0, 0);
        }
    }

    // ---- phase D: bias+relu+second-layer projections, reduce, CE ----
    float lg[4][5]; float lc[4][2];
    #pragma unroll
    for (int q = 0; q < 4; q++) {
        #pragma unroll
        for (int t = 0; t < 5; t++) lg[q][t] = 0.f;
        lc[q][0] = 0.f; lc[q][1] = 0.f;
    }
    #pragma unroll
    for (int t2 = 0; t2 < 4; t2++) {
        int c = t2 * 16 + frow;
        float bb = tsb1[c];
        float w0 = tsw2[c * 5 + 0], w1 = tsw2[c * 5 + 1], w2 = tsw2[c * 5 + 2],
              w3 = tsw2[c * 5 + 3], w4 = tsw2[c * 5 + 4];
        #pragma unroll
        for (int q = 0; q < 4; q++) {
            float v = fmaxf(a2c[t2][q] + bb, 0.f);
            lg[q][0] += v * w0; lg[q][1] += v * w1; lg[q][2] += v * w2;
            lg[q][3] += v * w3; lg[q][4] += v * w4;
        }
    }
    #pragma unroll
    for (int t2 = 0; t2 < 4; t2++) {
        int c = t2 * 16 + frow;
        float bb = cb1[c];
        float u0 = cw2[c * 2], u1 = cw2[c * 2 + 1];
        #pragma unroll
        for (int q = 0; q < 4; q++) {
            float v = fmaxf(a2c[t2 + 4][q] + bb, 0.f);
            lc[q][0] += v * u0; lc[q][1] += v * u1;
        }
    }
    #pragma unroll
    for (int q = 0; q < 4; q++) {
        #pragma unroll
        for (int t = 0; t < 5; t++) {
            lg[q][t] += __shfl_xor(lg[q][t], 1);
            lg[q][t] += __shfl_xor(lg[q][t], 2);
            lg[q][t] += __shfl_xor(lg[q][t], 4);
            lg[q][t] += __shfl_xor(lg[q][t], 8);
        }
        #pragma unroll
        for (int t = 0; t < 2; t++) {
            lc[q][t] += __shfl_xor(lc[q][t], 1);
            lc[q][t] += __shfl_xor(lc[q][t], 2);
            lc[q][t] += __shfl_xor(lc[q][t], 4);
            lc[q][t] += __shfl_xor(lc[q][t], 8);
        }
    }
    float tsl = 0.f, cll = 0.f, mval = 0.f;
    if (frow == 0) {
        #pragma unroll
        for (int q = 0; q < 4; q++) {
            int n = n0 + w * 16 + kg * 4 + q;
            if (n < NN) {
                float L[5];
                #pragma unroll
                for (int t = 0; t < 5; t++) L[t] = lg[q][t] + tsb2[t];
                float mx = fmaxf(fmaxf(fmaxf(L[0], L[1]), fmaxf(L[2], L[3])), L[4]);
                float se = 0.f;
                #pragma unroll
                for (int t = 0; t < 5; t++) se += __expf(L[t] - mx);
                int tg = tst[n];
                float pick = 0.f;
                #pragma unroll
                for (int t = 0; t < 5; t++) pick += (t == tg) ? L[t] : 0.f;
                tsl += mx + __logf(se) - pick;
                float C0 = lc[q][0] + cb2[0];
                float C1 = lc[q][1] + cb2[1];
                float mx2 = fmaxf(C0, C1);
                float lse2 = mx2 + __logf(__expf(C0 - mx2) + __expf(C1 - mx2));
                float mv = msk[n] ? 1.f : 0.f;
                float pick2 = ctg[n] ? C1 : C0;
                cll += (lse2 - pick2) * mv;
                mval += mv;
            }
        }
    }
    #pragma unroll
    for (int off = 1; off < 64; off <<= 1) {
        tsl  += __shfl_xor(tsl, off);
        cll  += __shfl_xor(cll, off);
        mval += __shfl_xor(mval, off);
    }
    if (l == 0) { red[w][0] = tsl; red[w][1] = cll; red[w][2] = mval; }
    __syncthreads();
    if (tid == 0) {
        part[blockIdx.x * 3 + 0] = red[0][0] + red[1][0] + red[2][0] + red[3][0];
        part[blockIdx.x * 3 + 1] = red[0][1] + red[1][1] + red[2][1] + red[3][1];
        part[blockIdx.x * 3 + 2] = red[0][2] + red[1][2] + red[2][2] + red[3][2];
    }
}

__global__ __launch_bounds__(256) void k_final(const float* part, float* out, int nb) {
    __shared__ float sm[3][256];
    int tid = threadIdx.x;
    float a = 0, b = 0, c = 0;
    for (int i = tid; i < nb; i += 256) { a += part[i*3]; b += part[i*3+1]; c += part[i*3+2]; }
    sm[0][tid] = a; sm[1][tid] = b; sm[2][tid] = c;
    __syncthreads();
    for (int s = 128; s > 0; s >>= 1) {
        if (tid < s) {
            sm[0][tid] += sm[0][tid + s];
            sm[1][tid] += sm[1][tid + s];
            sm[2][tid] += sm[2][tid + s];
        }
        __syncthreads();
    }
    if (tid == 0) out[0] = sm[1][0] / sm[2][0] + sm[0][0] / (float)NN;
}

// ---------------- host ----------------

extern "C" void kernel_launch(void* const* d_in, const int* in_sizes, int n_in,
                              void* d_out, int out_size, void* d_ws, size_t ws_size,
                              hipStream_t stream) {
    const float* x    = (const float*)d_in[0];
    const int*   ei   = (const int*)d_in[1];
    const int*   tst  = (const int*)d_in[2];
    const int*   ctg  = (const int*)d_in[3];
    const unsigned char* msk = (const unsigned char*)d_in[4];
    const float* W1   = (const float*)d_in[5];
    const float* a1s  = (const float*)d_in[6];
    const float* a1d  = (const float*)d_in[7];
    const float* b1   = (const float*)d_in[8];
    const float* W2   = (const float*)d_in[9];
    const float* a2s  = (const float*)d_in[10];
    const float* a2d  = (const float*)d_in[11];
    const float* b2   = (const float*)d_in[12];
    const float* tsw1 = (const float*)d_in[13];
    const float* tsb1 = (const float*)d_in[14];
    const float* tsw2 = (const float*)d_in[15];
    const float* tsb2 = (const float*)d_in[16];
    const float* cw1  = (const float*)d_in[17];
    const float* cb1  = (const float*)d_in[18];
    const float* cw2  = (const float*)d_in[19];
    const float* cb2  = (const float*)d_in[20];
    const int* srcE = ei;
    const int* dstE = ei + NE;

    char* ws = (char*)d_ws;
    size_t off = 0;
    auto alloc = [&](size_t b) { size_t o = off; off = (off + b + 255) & ~(size_t)255; return o; };
    int*   cnt    = (int*)(ws + alloc((size_t)NN * 4));
    int*   fill   = (int*)(ws + alloc((size_t)NN * 4));
    int*   rowptr = (int*)(ws + alloc((size_t)(NN + 1) * 4));
    int*   bsum   = (int*)(ws + alloc(128 * 4));
    int*   col    = (int*)(ws + alloc((size_t)NT * 4));
    int*   rowv   = (int*)(ws + alloc((size_t)NT * 4));
    float* aad1   = (float*)(ws + alloc((size_t)NN * 16 * 4));
    __hip_bfloat16* out1b = (__hip_bfloat16*)(ws + alloc((size_t)NN * 64 * 2));
    float* aad2   = (float*)(ws + alloc((size_t)NN * 16 * 4));
    float* wsd    = (float*)(ws + alloc(1024 * 4));
    __hip_bfloat16* W2pT  = (__hip_bfloat16*)(ws + alloc(32768 * 2));
    __hip_bfloat16* wB    = (__hip_bfloat16*)(ws + alloc(8192 * 2));
    unsigned* W1pT = (unsigned*)(ws + alloc(6144 * 4));
    float* zbuf   = (float*)(ws + alloc(256 * 4));
    __hip_bfloat16* h1b   = (__hip_bfloat16*)(ws + alloc((size_t)NN * 64 * 2));
    __hip_bfloat16* web   = (__hip_bfloat16*)(ws + alloc((size_t)NT * 8 * 2));
    float* part   = (float*)(ws + alloc((size_t)NODEB * 3 * 4));
    (void)ws_size; (void)in_sizes; (void)n_in; (void)out_size;

    int nb_scan = (NN + 1023) / 1024;  // 98

    k_misc<<<MISCGRID, 256, 0, stream>>>(W2, a2s, a2d, wsd, W2pT, cnt, fill,
                                         tsw1, cw1, wB, W1, W1pT, zbuf);
    k_count<<<(NE + 255) / 256, 256, 0, stream>>>(dstE, cnt);
    k_scanA<<<nb_scan, 256, 0, stream>>>(cnt, rowptr, bsum);
    k_scanC<<<(NN + 255) / 256, 256, 0, stream>>>(bsum, rowptr, nb_scan);
    k_fill<<<(NT + 255) / 256, 256, 0, stream>>>(srcE, dstE, rowptr, fill, col, rowv);

    k_gemm1<<<NN / G1ROWS, 128, 0, stream>>>(x, W1pT, a1s, a1d, zbuf, h1b, aad1);
    k_edgew<<<(NT + 255) / 256, 256, 0, stream>>>(aad1, col, rowv, web);
    k_agg1f<<<NN / 32, 256, 0, stream>>>(h1b, web, rowptr, col, b1, wsd, out1b, aad2);
    k_edgew<<<(NT + 255) / 256, 256, 0, stream>>>(aad2, col, rowv, web);

    k_l2f<<<NODEB, 256, 0, stream>>>(out1b, web, rowptr, col, W2pT, b2, wB,
                                     tsb1, cb1, tsw2, tsb2, cw2, cb2, tst, ctg, msk, part);

    k_final<<<1, 256, 0, stream>>>(part, (float*)d_out, NODEB);
}